// Round 1
// baseline (1265.942 us; speedup 1.0000x reference)
//
#include <hip/hip_runtime.h>
#include <hip/hip_bf16.h>

// GAT conv: H=4 heads, D=16 (H*D = 64) — hardcoded per reference constants.
// feat: (N_tot, 128) f32, W: (64,128), attn_l/r: (4,16), bias: (64,)
// edge_src: (E,) int in [0,NUM_SRC), edge_dst: (E,) int in [0,NUM_DST)
// out: (NUM_DST, 4, 16) f32

#define NEG_SLOPE 0.2f

__device__ __forceinline__ unsigned fenc(float f) {
    unsigned b = __float_as_uint(f);
    return (b & 0x80000000u) ? ~b : (b | 0x80000000u);
}
__device__ __forceinline__ float fdec(unsigned u) {
    unsigned b = (u & 0x80000000u) ? (u ^ 0x80000000u) : ~u;
    return __uint_as_float(b);
}

// ---- init: out = bias pattern; (m_enc, denom) zeroed via memsetAsync in launch ----
__global__ void k_init(float* __restrict__ out, const float* __restrict__ bias, int n_out) {
    int t = blockIdx.x * blockDim.x + threadIdx.x;
    if (t < n_out) out[t] = bias[t & 63];
}

// ---- projection + attention dots ----
// one node per thread; W^T staged in LDS [k][hd]; broadcast ds_read_b128 reads.
__global__ __launch_bounds__(256) void k_proj(
        const float* __restrict__ feat, const float* __restrict__ W,
        const float* __restrict__ attn_l, const float* __restrict__ attn_r,
        float* __restrict__ proj_src, float* __restrict__ el, float* __restrict__ er,
        int num_tot, int num_dst, int in_f) {
    __shared__ float wt[128][64];  // 32 KiB; wt[k][hd]
    // stage transposed: thread handles (k = i/64 fixed per pass, hd = i%64)
    // -> conflict-free LDS writes; strided global reads (W is 32KB, L2-hot).
    for (int i = threadIdx.x; i < 64 * in_f; i += 256) {
        int hd = i & 63, k = i >> 6;
        wt[k][hd] = W[hd * in_f + k];
    }
    __syncthreads();

    int n = blockIdx.x * 256 + threadIdx.x;
    if (n >= num_tot) return;

    float4 acc[16];
#pragma unroll
    for (int q = 0; q < 16; q++) acc[q] = float4{0.f, 0.f, 0.f, 0.f};

    const float* frow = feat + (size_t)n * in_f;
    for (int kc = 0; kc < in_f; kc += 32) {
        float4 f[8];
#pragma unroll
        for (int i = 0; i < 8; i++) f[i] = ((const float4*)(frow + kc))[i];
#pragma unroll
        for (int k = 0; k < 32; k++) {
            float fv = ((const float*)f)[k];
#pragma unroll
            for (int q = 0; q < 16; q++) {
                float4 w = *(const float4*)&wt[kc + k][q * 4];  // uniform addr -> broadcast
                acc[q].x += fv * w.x;
                acc[q].y += fv * w.y;
                acc[q].z += fv * w.z;
                acc[q].w += fv * w.w;
            }
        }
    }

    bool is_dst = (n < num_dst);
    const float* attn = is_dst ? attn_r : attn_l;
    float eh[4] = {0.f, 0.f, 0.f, 0.f};
#pragma unroll
    for (int q = 0; q < 16; q++) {
        float4 a4 = *(const float4*)&attn[q * 4];  // head = q>>2
        eh[q >> 2] += acc[q].x * a4.x + acc[q].y * a4.y + acc[q].z * a4.z + acc[q].w * a4.w;
    }

    if (is_dst) {
        *(float4*)&er[(size_t)n * 4] = float4{eh[0], eh[1], eh[2], eh[3]};
    } else {
        int s = n - num_dst;
        float* prow = proj_src + (size_t)s * 64;
#pragma unroll
        for (int q = 0; q < 16; q++) ((float4*)prow)[q] = acc[q];
        *(float4*)&el[(size_t)s * 4] = float4{eh[0], eh[1], eh[2], eh[3]};
    }
}

// ---- segment max over edges (encoded-uint atomicMax) ----
__global__ void k_max(const int* __restrict__ es, const int* __restrict__ ed,
                      const float* __restrict__ el, const float* __restrict__ er,
                      unsigned* __restrict__ m_enc, int E) {
    int t = blockIdx.x * blockDim.x + threadIdx.x;
    if (t >= E * 4) return;
    int e = t >> 2, h = t & 3;
    int s = es[e], d = ed[e];
    float x = el[s * 4 + h] + er[d * 4 + h];
    x = x > 0.f ? x : NEG_SLOPE * x;
    atomicMax(&m_enc[d * 4 + h], fenc(x));
}

// ---- softmax denominator ----
__global__ void k_denom(const int* __restrict__ es, const int* __restrict__ ed,
                        const float* __restrict__ el, const float* __restrict__ er,
                        const unsigned* __restrict__ m_enc, float* __restrict__ denom, int E) {
    int t = blockIdx.x * blockDim.x + threadIdx.x;
    if (t >= E * 4) return;
    int e = t >> 2, h = t & 3;
    int s = es[e], d = ed[e];
    float x = el[s * 4 + h] + er[d * 4 + h];
    x = x > 0.f ? x : NEG_SLOPE * x;
    float m = fdec(m_enc[d * 4 + h]);
    atomicAdd(&denom[d * 4 + h], __expf(x - m));
}

// ---- weighted message scatter ----
// thread = (edge, chunk c of 4 floats), 16 chunks cover the 64-wide row.
__global__ void k_scatter(const int* __restrict__ es, const int* __restrict__ ed,
                          const float* __restrict__ el, const float* __restrict__ er,
                          const unsigned* __restrict__ m_enc, const float* __restrict__ denom,
                          const float* __restrict__ proj_src, float* __restrict__ out, int E) {
    int t = blockIdx.x * blockDim.x + threadIdx.x;
    if (t >= E * 16) return;
    int e = t >> 4, c = t & 15, h = c >> 2;
    int s = es[e], d = ed[e];
    float x = el[s * 4 + h] + er[d * 4 + h];
    x = x > 0.f ? x : NEG_SLOPE * x;
    float m = fdec(m_enc[d * 4 + h]);
    float a = __expf(x - m) / denom[d * 4 + h];
    float4 p = *(const float4*)&proj_src[(size_t)s * 64 + c * 4];
    float* o = &out[(size_t)d * 64 + c * 4];
    atomicAdd(o + 0, p.x * a);
    atomicAdd(o + 1, p.y * a);
    atomicAdd(o + 2, p.z * a);
    atomicAdd(o + 3, p.w * a);
}

extern "C" void kernel_launch(void* const* d_in, const int* in_sizes, int n_in,
                              void* d_out, int out_size, void* d_ws, size_t ws_size,
                              hipStream_t stream) {
    const float* feat   = (const float*)d_in[0];
    const float* W      = (const float*)d_in[1];
    const float* attn_l = (const float*)d_in[2];
    const float* attn_r = (const float*)d_in[3];
    const float* bias   = (const float*)d_in[4];
    const int*   es     = (const int*)d_in[5];
    const int*   ed     = (const int*)d_in[6];

    const int HD      = in_sizes[2];            // 64
    const int in_f    = in_sizes[1] / HD;       // 128
    const int num_dst = out_size / HD;          // 50000
    const int num_tot = in_sizes[0] / in_f;     // 150000
    const int num_src = num_tot - num_dst;      // 100000
    const int E       = in_sizes[5];            // 1200000

    float* out = (float*)d_out;

    // ws layout
    float*    proj_src = (float*)d_ws;                       // num_src*64
    float*    el       = proj_src + (size_t)num_src * 64;    // num_src*4
    float*    er       = el + (size_t)num_src * 4;           // num_dst*4
    unsigned* m_enc    = (unsigned*)(er + (size_t)num_dst * 4); // num_dst*4
    float*    denom    = (float*)(m_enc + (size_t)num_dst * 4); // num_dst*4

    // zero m_enc + denom in one shot (contiguous); enc(0)=... note enc init 0 < enc(x) for all x
    hipMemsetAsync(m_enc, 0, (size_t)num_dst * 4 * sizeof(unsigned) * 2, stream);

    int n_out = num_dst * HD;
    k_init<<<(n_out + 255) / 256, 256, 0, stream>>>(out, bias, n_out);

    k_proj<<<(num_tot + 255) / 256, 256, 0, stream>>>(
        feat, W, attn_l, attn_r, proj_src, el, er, num_tot, num_dst, in_f);

    k_max<<<((size_t)E * 4 + 255) / 256, 256, 0, stream>>>(es, ed, el, er, m_enc, E);

    k_denom<<<((size_t)E * 4 + 255) / 256, 256, 0, stream>>>(es, ed, el, er, m_enc, denom, E);

    k_scatter<<<((size_t)E * 16 + 255) / 256, 256, 0, stream>>>(
        es, ed, el, er, m_enc, denom, proj_src, out, E);
}

// Round 2
// 352.992 us; speedup vs baseline: 3.5863x; 3.5863x over previous
//
#include <hip/hip_runtime.h>
#include <hip/hip_bf16.h>

// GAT conv: H=4 heads, D=16 (H*D = 64) — hardcoded per reference constants.
// feat: (N_tot, 128) f32, W: (64,128), attn_l/r: (4,16), bias: (64,)
// edge_src: (E,) int in [0,NUM_SRC), edge_dst: (E,) int in [0,NUM_DST)
// out: (NUM_DST, 4, 16) f32
//
// Strategy: projection (VALU fp32) -> CSR build by dst (hist+scan+fill)
// -> one wave per dst gathers its edges: online softmax (m,denom) then
// weighted sum of proj_src rows in registers. Zero float atomics.

#define NEG_SLOPE 0.2f

// ---- projection + attention dots ----
// one node per thread; W^T staged in LDS [k][hd]; broadcast ds_read_b128 reads.
__global__ __launch_bounds__(256) void k_proj(
        const float* __restrict__ feat, const float* __restrict__ W,
        const float* __restrict__ attn_l, const float* __restrict__ attn_r,
        float* __restrict__ proj_src, float* __restrict__ el, float* __restrict__ er,
        int num_tot, int num_dst, int in_f) {
    __shared__ float wt[128][64];  // 32 KiB; wt[k][hd]
    for (int i = threadIdx.x; i < 64 * in_f; i += 256) {
        int hd = i & 63, k = i >> 6;
        wt[k][hd] = W[hd * in_f + k];
    }
    __syncthreads();

    int n = blockIdx.x * 256 + threadIdx.x;
    if (n >= num_tot) return;

    float4 acc[16];
#pragma unroll
    for (int q = 0; q < 16; q++) acc[q] = float4{0.f, 0.f, 0.f, 0.f};

    const float* frow = feat + (size_t)n * in_f;
    for (int kc = 0; kc < in_f; kc += 32) {
        float4 f[8];
#pragma unroll
        for (int i = 0; i < 8; i++) f[i] = ((const float4*)(frow + kc))[i];
#pragma unroll
        for (int k = 0; k < 32; k++) {
            float fv = ((const float*)f)[k];
#pragma unroll
            for (int q = 0; q < 16; q++) {
                float4 w = *(const float4*)&wt[kc + k][q * 4];  // uniform addr -> broadcast
                acc[q].x += fv * w.x;
                acc[q].y += fv * w.y;
                acc[q].z += fv * w.z;
                acc[q].w += fv * w.w;
            }
        }
    }

    bool is_dst = (n < num_dst);
    const float* attn = is_dst ? attn_r : attn_l;
    float eh[4] = {0.f, 0.f, 0.f, 0.f};
#pragma unroll
    for (int q = 0; q < 16; q++) {
        float4 a4 = *(const float4*)&attn[q * 4];  // head = q>>2
        eh[q >> 2] += acc[q].x * a4.x + acc[q].y * a4.y + acc[q].z * a4.z + acc[q].w * a4.w;
    }

    if (is_dst) {
        *(float4*)&er[(size_t)n * 4] = float4{eh[0], eh[1], eh[2], eh[3]};
    } else {
        int s = n - num_dst;
        float* prow = proj_src + (size_t)s * 64;
#pragma unroll
        for (int q = 0; q < 16; q++) ((float4*)prow)[q] = acc[q];
        *(float4*)&el[(size_t)s * 4] = float4{eh[0], eh[1], eh[2], eh[3]};
    }
}

// ---- CSR build: histogram ----
__global__ void k_hist(const int* __restrict__ ed, int* __restrict__ counts, int E) {
    int t = blockIdx.x * blockDim.x + threadIdx.x;
    if (t < E) atomicAdd(&counts[ed[t]], 1);
}

// ---- scan step 1: per-block (1024-wide) exclusive scan ----
__global__ __launch_bounds__(1024) void k_scan_block(
        const int* __restrict__ counts, int* __restrict__ offs,
        int* __restrict__ bsums, int nd) {
    __shared__ int sh[1024];
    int i = blockIdx.x * 1024 + threadIdx.x;
    int c = (i < nd) ? counts[i] : 0;
    sh[threadIdx.x] = c;
    __syncthreads();
    for (int off = 1; off < 1024; off <<= 1) {
        int v = (threadIdx.x >= off) ? sh[threadIdx.x - off] : 0;
        __syncthreads();
        sh[threadIdx.x] += v;
        __syncthreads();
    }
    int inc = sh[threadIdx.x];
    if (i < nd) offs[i] = inc - c;  // exclusive within block
    if (threadIdx.x == 1023) bsums[blockIdx.x] = inc;
}

// ---- scan step 2: single-wave exclusive scan of block sums (nb <= 64) ----
__global__ void k_scan_tops(int* __restrict__ bsums, int nb) {
    int lane = threadIdx.x;
    int v = (lane < nb) ? bsums[lane] : 0;
#pragma unroll
    for (int off = 1; off < 64; off <<= 1) {
        int u = __shfl_up(v, off, 64);
        if (lane >= off) v += u;
    }
    int ex = __shfl_up(v, 1, 64);
    if (lane == 0) ex = 0;
    if (lane < nb) bsums[lane] = ex;
}

// ---- scan step 3: add block offsets; also init fill cursor ----
__global__ void k_scan_add(int* __restrict__ offs, int* __restrict__ cursor,
                           const int* __restrict__ bsums, int nd) {
    int i = blockIdx.x * blockDim.x + threadIdx.x;
    if (i >= nd) return;
    int o = offs[i] + bsums[i >> 10];
    offs[i] = o;
    cursor[i] = o;
}

// ---- CSR fill: csr_src[slot] = src id ----
__global__ void k_fill(const int* __restrict__ es, const int* __restrict__ ed,
                       int* __restrict__ cursor, int* __restrict__ csr_src, int E) {
    int t = blockIdx.x * blockDim.x + threadIdx.x;
    if (t >= E) return;
    int d = ed[t];
    int pos = atomicAdd(&cursor[d], 1);
    csr_src[pos] = es[t];
}

// ---- aggregate: one wave per dst; lane = output column (h*16 + dcol) ----
__global__ __launch_bounds__(256) void k_agg(
        const int* __restrict__ csr_src, const int* __restrict__ offs,
        const int* __restrict__ counts, const float* __restrict__ el,
        const float* __restrict__ er, const float* __restrict__ proj_src,
        const float* __restrict__ bias, float* __restrict__ out, int nd) {
    int wave = (blockIdx.x * 256 + threadIdx.x) >> 6;
    int lane = threadIdx.x & 63;
    if (wave >= nd) return;
    int d = wave;
    int h = lane >> 4;
    int start = offs[d], deg = counts[d];
    float er_h = er[d * 4 + h];

    // pass 1: online (m, den); lane j=(lane&15) strides edges by 16
    float m = -INFINITY, den = 0.f;
    for (int j = (lane & 15); j < deg; j += 16) {
        int s = csr_src[start + j];
        float x = el[s * 4 + h] + er_h;
        x = x > 0.f ? x : NEG_SLOPE * x;
        if (x > m) {
            den = den * __expf(m - x) + 1.f;  // exp(-inf)=0 on first hit, 0*0=0 ok
            m = x;
        } else {
            den += __expf(x - m);
        }
    }
    // merge across the 16-lane head group (xor stays within group)
#pragma unroll
    for (int off = 1; off < 16; off <<= 1) {
        float mo = __shfl_xor(m, off, 64);
        float dn = __shfl_xor(den, off, 64);
        float mn = fmaxf(m, mo);
        float sa = (m == -INFINITY) ? 0.f : __expf(m - mn);
        float sb = (mo == -INFINITY) ? 0.f : __expf(mo - mn);
        den = den * sa + dn * sb;
        m = mn;
    }
    float rden = (den > 0.f) ? 1.f / den : 0.f;

    // pass 2: all 64 lanes walk edges together; coalesced 256B proj gather
    float acc = 0.f;
    int j = 0;
    for (; j + 2 <= deg; j += 2) {  // 2-edge unroll for load ILP
        int s0 = csr_src[start + j];
        int s1 = csr_src[start + j + 1];
        float x0 = el[s0 * 4 + h] + er_h;
        float x1 = el[s1 * 4 + h] + er_h;
        float p0 = proj_src[(size_t)s0 * 64 + lane];
        float p1 = proj_src[(size_t)s1 * 64 + lane];
        x0 = x0 > 0.f ? x0 : NEG_SLOPE * x0;
        x1 = x1 > 0.f ? x1 : NEG_SLOPE * x1;
        acc += __expf(x0 - m) * rden * p0;
        acc += __expf(x1 - m) * rden * p1;
    }
    if (j < deg) {
        int s = csr_src[start + j];
        float x = el[s * 4 + h] + er_h;
        x = x > 0.f ? x : NEG_SLOPE * x;
        acc += __expf(x - m) * rden * proj_src[(size_t)s * 64 + lane];
    }

    out[(size_t)d * 64 + lane] = acc + bias[lane];
}

extern "C" void kernel_launch(void* const* d_in, const int* in_sizes, int n_in,
                              void* d_out, int out_size, void* d_ws, size_t ws_size,
                              hipStream_t stream) {
    const float* feat   = (const float*)d_in[0];
    const float* W      = (const float*)d_in[1];
    const float* attn_l = (const float*)d_in[2];
    const float* attn_r = (const float*)d_in[3];
    const float* bias   = (const float*)d_in[4];
    const int*   es     = (const int*)d_in[5];
    const int*   ed     = (const int*)d_in[6];

    const int HD      = in_sizes[2];            // 64
    const int in_f    = in_sizes[1] / HD;       // 128
    const int num_dst = out_size / HD;          // 50000
    const int num_tot = in_sizes[0] / in_f;     // 150000
    const int num_src = num_tot - num_dst;      // 100000
    const int E       = in_sizes[5];            // 1200000

    float* out = (float*)d_out;

    // ws layout (all 4-byte elements)
    float* proj_src = (float*)d_ws;                          // num_src*64
    float* el       = proj_src + (size_t)num_src * 64;       // num_src*4
    float* er       = el + (size_t)num_src * 4;              // num_dst*4
    int*   counts   = (int*)(er + (size_t)num_dst * 4);      // num_dst
    int*   offs     = counts + num_dst;                      // num_dst
    int*   cursor   = offs + num_dst;                        // num_dst
    int*   bsums    = cursor + num_dst;                      // <=64
    int*   csr_src  = bsums + 64;                            // E

    const int nb = (num_dst + 1023) / 1024;                  // 49 (<=64 required)

    hipMemsetAsync(counts, 0, (size_t)num_dst * sizeof(int), stream);

    k_proj<<<(num_tot + 255) / 256, 256, 0, stream>>>(
        feat, W, attn_l, attn_r, proj_src, el, er, num_tot, num_dst, in_f);

    k_hist<<<(E + 255) / 256, 256, 0, stream>>>(ed, counts, E);
    k_scan_block<<<nb, 1024, 0, stream>>>(counts, offs, bsums, num_dst);
    k_scan_tops<<<1, 64, 0, stream>>>(bsums, nb);
    k_scan_add<<<(num_dst + 255) / 256, 256, 0, stream>>>(offs, cursor, bsums, num_dst);
    k_fill<<<(E + 255) / 256, 256, 0, stream>>>(es, ed, cursor, csr_src, E);

    k_agg<<<(num_dst * 64 + 255) / 256, 256, 0, stream>>>(
        csr_src, offs, counts, el, er, proj_src, bias, out, num_dst);
}

// Round 3
// 282.394 us; speedup vs baseline: 4.4829x; 1.2500x over previous
//
#include <hip/hip_runtime.h>
#include <hip/hip_bf16.h>

// GAT conv: H=4 heads, D=16 (H*D = 64) — hardcoded per reference constants.
// feat: (N_tot, 128) f32, W: (64,128), attn_l/r: (4,16), bias: (64,)
// out: (NUM_DST, 4, 16) f32
//
// Pipeline: W->bf16 | MFMA projection (+fused el/er dots) | CSR build by dst
// (hist+scan+fill) | per-dst-wave gather aggregate. Zero float atomics.

#define NEG_SLOPE 0.2f

typedef __attribute__((ext_vector_type(8))) short bf16x8;  // 8 bf16 (4 VGPRs)
typedef __attribute__((ext_vector_type(4))) float f32x4;

__device__ __forceinline__ short f2bf(float f) {  // RNE f32->bf16 bits
    unsigned u = __float_as_uint(f);
    unsigned r = (u + 0x7fffu + ((u >> 16) & 1u)) >> 16;
    return (short)r;
}

// ---- W fp32 -> bf16 (8192 elems) ----
__global__ void k_wcvt(const float* __restrict__ W, short* __restrict__ Wb, int n) {
    int t = blockIdx.x * blockDim.x + threadIdx.x;
    if (t < n) Wb[t] = f2bf(W[t]);
}

// ---- MFMA projection + fused attention dots ----
// block = 256 (4 waves); wave = 16 nodes x 64 outs, K=128 -> 16 MFMA 16x16x32.
// A: lane holds feat[nbase + (lane&15)][(lane>>4)*8 + j + 32c]  (bf16, in-reg cvt)
// B: lane holds Wb[(h*16 + (lane&15))*128 + (lane>>4)*8 + j + 32c]
// C: acc[h][r] = proj[nbase + (lane>>4)*4 + r][h*16 + (lane&15)]
__global__ __launch_bounds__(256) void k_proj(
        const float* __restrict__ feat, const short* __restrict__ Wb,
        const float* __restrict__ attn_l, const float* __restrict__ attn_r,
        float* __restrict__ proj_src, float* __restrict__ el, float* __restrict__ er,
        int num_tot, int num_dst) {
    const int lane = threadIdx.x & 63;
    const int wv = threadIdx.x >> 6;
    const int lr = lane & 15;
    const int lg = lane >> 4;
    const int nbase = blockIdx.x * 64 + wv * 16;

    int arow = nbase + lr;
    if (arow >= num_tot) arow = num_tot - 1;  // clamp; stores are guarded
    const float* ap = feat + (size_t)arow * 128 + lg * 8;
    bf16x8 afrag[4];
#pragma unroll
    for (int c = 0; c < 4; c++) {
        float4 x = *(const float4*)(ap + c * 32);
        float4 y = *(const float4*)(ap + c * 32 + 4);
        bf16x8 t;
        t[0] = f2bf(x.x); t[1] = f2bf(x.y); t[2] = f2bf(x.z); t[3] = f2bf(x.w);
        t[4] = f2bf(y.x); t[5] = f2bf(y.y); t[6] = f2bf(y.z); t[7] = f2bf(y.w);
        afrag[c] = t;
    }

    f32x4 acc[4];
#pragma unroll
    for (int h = 0; h < 4; h++) acc[h] = f32x4{0.f, 0.f, 0.f, 0.f};
#pragma unroll
    for (int h = 0; h < 4; h++) {
        const short* bp = Wb + (h * 16 + lr) * 128 + lg * 8;
#pragma unroll
        for (int c = 0; c < 4; c++) {
            bf16x8 b = *(const bf16x8*)(bp + c * 32);  // 16B aligned
            acc[h] = __builtin_amdgcn_mfma_f32_16x16x32_bf16(afrag[c], b, acc[h], 0, 0, 0);
        }
    }

    // proj store (src rows only)
    const int rbase = nbase + lg * 4;
#pragma unroll
    for (int r = 0; r < 4; r++) {
        int n = rbase + r;
        if (n >= num_dst && n < num_tot) {
            float* prow = proj_src + (size_t)(n - num_dst) * 64;
#pragma unroll
            for (int h = 0; h < 4; h++) prow[h * 16 + lr] = acc[h][r];
        }
    }

    // fused el/er: row-sum of acc[h] * attn[h][col] over the 16-lane col group
#pragma unroll
    for (int h = 0; h < 4; h++) {
        float al = attn_l[h * 16 + lr];
        float ar = attn_r[h * 16 + lr];
#pragma unroll
        for (int r = 0; r < 4; r++) {
            int n = rbase + r;
            float v = acc[h][r] * ((n < num_dst) ? ar : al);
            v += __shfl_xor(v, 1);
            v += __shfl_xor(v, 2);
            v += __shfl_xor(v, 4);
            v += __shfl_xor(v, 8);
            if (lr == h) {
                if (n < num_dst) er[(size_t)n * 4 + h] = v;
                else if (n < num_tot) el[(size_t)(n - num_dst) * 4 + h] = v;
            }
        }
    }
}

// ---- CSR build: histogram ----
__global__ void k_hist(const int* __restrict__ ed, int* __restrict__ counts, int E) {
    int t = blockIdx.x * blockDim.x + threadIdx.x;
    if (t < E) atomicAdd(&counts[ed[t]], 1);
}

// ---- scan step 1: per-block (1024-wide) exclusive scan ----
__global__ __launch_bounds__(1024) void k_scan_block(
        const int* __restrict__ counts, int* __restrict__ offs,
        int* __restrict__ bsums, int nd) {
    __shared__ int sh[1024];
    int i = blockIdx.x * 1024 + threadIdx.x;
    int c = (i < nd) ? counts[i] : 0;
    sh[threadIdx.x] = c;
    __syncthreads();
    for (int off = 1; off < 1024; off <<= 1) {
        int v = (threadIdx.x >= off) ? sh[threadIdx.x - off] : 0;
        __syncthreads();
        sh[threadIdx.x] += v;
        __syncthreads();
    }
    int inc = sh[threadIdx.x];
    if (i < nd) offs[i] = inc - c;
    if (threadIdx.x == 1023) bsums[blockIdx.x] = inc;
}

// ---- scan step 2: single-wave exclusive scan of block sums (nb <= 64) ----
__global__ void k_scan_tops(int* __restrict__ bsums, int nb) {
    int lane = threadIdx.x;
    int v = (lane < nb) ? bsums[lane] : 0;
#pragma unroll
    for (int off = 1; off < 64; off <<= 1) {
        int u = __shfl_up(v, off, 64);
        if (lane >= off) v += u;
    }
    int ex = __shfl_up(v, 1, 64);
    if (lane == 0) ex = 0;
    if (lane < nb) bsums[lane] = ex;
}

// ---- scan step 3: add block offsets; init fill cursor ----
__global__ void k_scan_add(int* __restrict__ offs, int* __restrict__ cursor,
                           const int* __restrict__ bsums, int nd) {
    int i = blockIdx.x * blockDim.x + threadIdx.x;
    if (i >= nd) return;
    int o = offs[i] + bsums[i >> 10];
    offs[i] = o;
    cursor[i] = o;
}

// ---- CSR fill ----
__global__ void k_fill(const int* __restrict__ es, const int* __restrict__ ed,
                       int* __restrict__ cursor, int* __restrict__ csr_src, int E) {
    int t = blockIdx.x * blockDim.x + threadIdx.x;
    if (t >= E) return;
    int d = ed[t];
    int pos = atomicAdd(&cursor[d], 1);
    csr_src[pos] = es[t];
}

// ---- aggregate: one wave per dst; lane = output column ----
__global__ __launch_bounds__(256) void k_agg(
        const int* __restrict__ csr_src, const int* __restrict__ offs,
        const int* __restrict__ counts, const float* __restrict__ el,
        const float* __restrict__ er, const float* __restrict__ proj_src,
        const float* __restrict__ bias, float* __restrict__ out, int nd) {
    int wave = (blockIdx.x * 256 + threadIdx.x) >> 6;
    int lane = threadIdx.x & 63;
    if (wave >= nd) return;
    int d = wave;
    int h = lane >> 4;
    int start = offs[d], deg = counts[d];
    float er_h = er[d * 4 + h];

    // pass 1: online (m, den); lane j=(lane&15) strides edges by 16
    float m = -INFINITY, den = 0.f;
    for (int j = (lane & 15); j < deg; j += 16) {
        int s = csr_src[start + j];
        float x = el[s * 4 + h] + er_h;
        x = x > 0.f ? x : NEG_SLOPE * x;
        if (x > m) {
            den = den * __expf(m - x) + 1.f;
            m = x;
        } else {
            den += __expf(x - m);
        }
    }
#pragma unroll
    for (int off = 1; off < 16; off <<= 1) {
        float mo = __shfl_xor(m, off, 64);
        float dn = __shfl_xor(den, off, 64);
        float mn = fmaxf(m, mo);
        float sa = (m == -INFINITY) ? 0.f : __expf(m - mn);
        float sb = (mo == -INFINITY) ? 0.f : __expf(mo - mn);
        den = den * sa + dn * sb;
        m = mn;
    }
    float rden = (den > 0.f) ? 1.f / den : 0.f;

    // pass 2: all 64 lanes walk edges; coalesced 256B proj gather
    float acc = 0.f;
    int j = 0;
    for (; j + 2 <= deg; j += 2) {
        int s0 = csr_src[start + j];
        int s1 = csr_src[start + j + 1];
        float x0 = el[s0 * 4 + h] + er_h;
        float x1 = el[s1 * 4 + h] + er_h;
        float p0 = proj_src[(size_t)s0 * 64 + lane];
        float p1 = proj_src[(size_t)s1 * 64 + lane];
        x0 = x0 > 0.f ? x0 : NEG_SLOPE * x0;
        x1 = x1 > 0.f ? x1 : NEG_SLOPE * x1;
        acc += __expf(x0 - m) * rden * p0;
        acc += __expf(x1 - m) * rden * p1;
    }
    if (j < deg) {
        int s = csr_src[start + j];
        float x = el[s * 4 + h] + er_h;
        x = x > 0.f ? x : NEG_SLOPE * x;
        acc += __expf(x - m) * rden * proj_src[(size_t)s * 64 + lane];
    }

    out[(size_t)d * 64 + lane] = acc + bias[lane];
}

extern "C" void kernel_launch(void* const* d_in, const int* in_sizes, int n_in,
                              void* d_out, int out_size, void* d_ws, size_t ws_size,
                              hipStream_t stream) {
    const float* feat   = (const float*)d_in[0];
    const float* W      = (const float*)d_in[1];
    const float* attn_l = (const float*)d_in[2];
    const float* attn_r = (const float*)d_in[3];
    const float* bias   = (const float*)d_in[4];
    const int*   es     = (const int*)d_in[5];
    const int*   ed     = (const int*)d_in[6];

    const int HD      = in_sizes[2];            // 64
    const int in_f    = in_sizes[1] / HD;       // 128
    const int num_dst = out_size / HD;          // 50000
    const int num_tot = in_sizes[0] / in_f;     // 150000
    const int num_src = num_tot - num_dst;      // 100000
    const int E       = in_sizes[5];            // 1200000

    float* out = (float*)d_out;

    // ws layout (all 4-byte elements; every section a multiple of 4 elems -> 16B aligned)
    float* proj_src = (float*)d_ws;                          // num_src*64
    float* el       = proj_src + (size_t)num_src * 64;       // num_src*4
    float* er       = el + (size_t)num_src * 4;              // num_dst*4
    int*   counts   = (int*)(er + (size_t)num_dst * 4);      // num_dst
    int*   offs     = counts + num_dst;                      // num_dst
    int*   cursor   = offs + num_dst;                        // num_dst
    int*   bsums    = cursor + num_dst;                      // <=64
    int*   csr_src  = bsums + 64;                            // E

    // W_bf16 aliases csr_src: k_proj reads it before k_fill overwrites (stream-ordered).
    short* Wb = (short*)csr_src;

    const int nb = (num_dst + 1023) / 1024;                  // 49 (<=64 required)

    hipMemsetAsync(counts, 0, (size_t)num_dst * sizeof(int), stream);

    k_wcvt<<<(HD * in_f + 255) / 256, 256, 0, stream>>>(W, Wb, HD * in_f);

    k_proj<<<(num_tot + 63) / 64, 256, 0, stream>>>(
        feat, Wb, attn_l, attn_r, proj_src, el, er, num_tot, num_dst);

    k_hist<<<(E + 255) / 256, 256, 0, stream>>>(ed, counts, E);
    k_scan_block<<<nb, 1024, 0, stream>>>(counts, offs, bsums, num_dst);
    k_scan_tops<<<1, 64, 0, stream>>>(bsums, nb);
    k_scan_add<<<(num_dst + 255) / 256, 256, 0, stream>>>(offs, cursor, bsums, num_dst);
    k_fill<<<(E + 255) / 256, 256, 0, stream>>>(es, ed, cursor, csr_src, E);

    k_agg<<<(num_dst * 64 + 255) / 256, 256, 0, stream>>>(
        csr_src, offs, counts, el, er, proj_src, bias, out, num_dst);
}

// Round 4
// 190.802 us; speedup vs baseline: 6.6349x; 1.4800x over previous
//
#include <hip/hip_runtime.h>
#include <hip/hip_bf16.h>

// GAT conv: H=4 heads, D=16 (H*D = 64) — hardcoded per reference constants.
// feat: (N_tot, 128) f32, W: (64,128), attn_l/r: (4,16), bias: (64,)
// out: (NUM_DST, 4, 16) f32
//
// Pipeline: W->bf16 | MFMA projection (+fused el/er dots) | two-level CSR
// build (bucket hist -> scan -> bucket bin -> per-bucket fine fill, all
// XCD-local scatters) | per-dst-wave gather aggregate. Zero float atomics.

#define NEG_SLOPE 0.2f
#define BSHIFT 7                 // bucket = dst >> 7 (128 dsts per bucket)
#define BMASK  127
#define MAXBUK 512               // supports num_dst <= 65536
#define BCAP   6144              // max edges per bucket (mean ~3070, Poisson tail << 6144)

typedef __attribute__((ext_vector_type(8))) short bf16x8;  // 8 bf16 (4 VGPRs)
typedef __attribute__((ext_vector_type(4))) float f32x4;

__device__ __forceinline__ short f2bf(float f) {  // RNE f32->bf16 bits
    unsigned u = __float_as_uint(f);
    unsigned r = (u + 0x7fffu + ((u >> 16) & 1u)) >> 16;
    return (short)r;
}

// ---- W fp32 -> bf16 (8192 elems) ----
__global__ void k_wcvt(const float* __restrict__ W, short* __restrict__ Wb, int n) {
    int t = blockIdx.x * blockDim.x + threadIdx.x;
    if (t < n) Wb[t] = f2bf(W[t]);
}

// ---- MFMA projection + fused attention dots ----
// block = 256 (4 waves); wave = 16 nodes x 64 outs, K=128 -> 16 MFMA 16x16x32.
__global__ __launch_bounds__(256) void k_proj(
        const float* __restrict__ feat, const short* __restrict__ Wb,
        const float* __restrict__ attn_l, const float* __restrict__ attn_r,
        float* __restrict__ proj_src, float* __restrict__ el, float* __restrict__ er,
        int num_tot, int num_dst) {
    const int lane = threadIdx.x & 63;
    const int wv = threadIdx.x >> 6;
    const int lr = lane & 15;
    const int lg = lane >> 4;
    const int nbase = blockIdx.x * 64 + wv * 16;

    int arow = nbase + lr;
    if (arow >= num_tot) arow = num_tot - 1;  // clamp; stores are guarded
    const float* ap = feat + (size_t)arow * 128 + lg * 8;
    bf16x8 afrag[4];
#pragma unroll
    for (int c = 0; c < 4; c++) {
        float4 x = *(const float4*)(ap + c * 32);
        float4 y = *(const float4*)(ap + c * 32 + 4);
        bf16x8 t;
        t[0] = f2bf(x.x); t[1] = f2bf(x.y); t[2] = f2bf(x.z); t[3] = f2bf(x.w);
        t[4] = f2bf(y.x); t[5] = f2bf(y.y); t[6] = f2bf(y.z); t[7] = f2bf(y.w);
        afrag[c] = t;
    }

    f32x4 acc[4];
#pragma unroll
    for (int h = 0; h < 4; h++) acc[h] = f32x4{0.f, 0.f, 0.f, 0.f};
#pragma unroll
    for (int h = 0; h < 4; h++) {
        const short* bp = Wb + (h * 16 + lr) * 128 + lg * 8;
#pragma unroll
        for (int c = 0; c < 4; c++) {
            bf16x8 b = *(const bf16x8*)(bp + c * 32);
            acc[h] = __builtin_amdgcn_mfma_f32_16x16x32_bf16(afrag[c], b, acc[h], 0, 0, 0);
        }
    }

    // proj store (src rows only)
    const int rbase = nbase + lg * 4;
#pragma unroll
    for (int r = 0; r < 4; r++) {
        int n = rbase + r;
        if (n >= num_dst && n < num_tot) {
            float* prow = proj_src + (size_t)(n - num_dst) * 64;
#pragma unroll
            for (int h = 0; h < 4; h++) prow[h * 16 + lr] = acc[h][r];
        }
    }

    // fused el/er: row-sum of acc[h] * attn[h][col] over the 16-lane col group
#pragma unroll
    for (int h = 0; h < 4; h++) {
        float al = attn_l[h * 16 + lr];
        float ar = attn_r[h * 16 + lr];
#pragma unroll
        for (int r = 0; r < 4; r++) {
            int n = rbase + r;
            float v = acc[h][r] * ((n < num_dst) ? ar : al);
            v += __shfl_xor(v, 1);
            v += __shfl_xor(v, 2);
            v += __shfl_xor(v, 4);
            v += __shfl_xor(v, 8);
            if (lr == h) {
                if (n < num_dst) er[(size_t)n * 4 + h] = v;
                else if (n < num_tot) el[(size_t)(n - num_dst) * 4 + h] = v;
            }
        }
    }
}

// ---- bucket histogram: LDS pre-aggregation, one global atomic per (block,bucket) ----
__global__ __launch_bounds__(256) void k_bhist(const int* __restrict__ ed,
                                               int* __restrict__ bukcnt, int E, int nbuk) {
    __shared__ int h[MAXBUK];
    for (int i = threadIdx.x; i < MAXBUK; i += 256) h[i] = 0;
    __syncthreads();
    int base = blockIdx.x * 4096;
#pragma unroll
    for (int i = 0; i < 16; i++) {
        int idx = base + threadIdx.x + i * 256;
        if (idx < E) atomicAdd(&h[ed[idx] >> BSHIFT], 1);
    }
    __syncthreads();
    for (int i = threadIdx.x; i < nbuk; i += 256)
        if (h[i]) atomicAdd(&bukcnt[i], h[i]);
}

// ---- exclusive scan of bucket counts (nbuk <= 512), init cursors ----
__global__ __launch_bounds__(512) void k_bscan(const int* __restrict__ bukcnt,
                                               int* __restrict__ bukstart,
                                               int* __restrict__ bukcur, int nbuk) {
    __shared__ int sh[MAXBUK];
    int tid = threadIdx.x;
    int c = (tid < nbuk) ? bukcnt[tid] : 0;
    sh[tid] = c;
    __syncthreads();
    for (int off = 1; off < MAXBUK; off <<= 1) {
        int v = (tid >= off) ? sh[tid - off] : 0;
        __syncthreads();
        sh[tid] += v;
        __syncthreads();
    }
    int ex = sh[tid] - c;
    if (tid < nbuk) { bukstart[tid] = ex; bukcur[tid] = ex; }
}

// ---- coarse bin: scatter packed (src | dloc<<25) into bucket runs ----
// requires num_src < 2^25 (here 100000). Runs of ~21 edges -> near-full-line writes.
__global__ __launch_bounds__(256) void k_bin(const int* __restrict__ es,
                                             const int* __restrict__ ed,
                                             int* __restrict__ bukcur,
                                             unsigned* __restrict__ pairs, int E, int nbuk) {
    __shared__ int h[MAXBUK];
    __shared__ int cur[MAXBUK];
    for (int i = threadIdx.x; i < MAXBUK; i += 256) h[i] = 0;
    __syncthreads();
    int base = blockIdx.x * 8192;
#pragma unroll
    for (int i = 0; i < 32; i++) {
        int idx = base + threadIdx.x + i * 256;
        if (idx < E) atomicAdd(&h[ed[idx] >> BSHIFT], 1);
    }
    __syncthreads();
    for (int i = threadIdx.x; i < nbuk; i += 256)
        cur[i] = h[i] ? atomicAdd(&bukcur[i], h[i]) : 0;
    __syncthreads();
#pragma unroll
    for (int i = 0; i < 32; i++) {
        int idx = base + threadIdx.x + i * 256;
        if (idx < E) {
            int d = ed[idx];
            int pos = atomicAdd(&cur[d >> BSHIFT], 1);
            pairs[pos] = (unsigned)es[idx] | ((unsigned)(d & BMASK) << 25);
        }
    }
}

// ---- fine fill: one block per bucket; LDS-staged in-place permute to CSR;
//      also emits offs[] and counts[] (replaces the old hist+scan kernels). ----
__global__ __launch_bounds__(256) void k_fillb(unsigned* __restrict__ pairs,
                                               const int* __restrict__ bukstart,
                                               const int* __restrict__ bukcnt,
                                               int* __restrict__ offs,
                                               int* __restrict__ counts, int nd) {
    __shared__ unsigned lp[BCAP];
    __shared__ int h[128], ex[128], cur[128];
    int b = blockIdx.x;
    int s = bukstart[b];
    int cnt = bukcnt[b];
    if (cnt > BCAP) cnt = BCAP;  // statistically impossible; guard anyway
    if (threadIdx.x < 128) h[threadIdx.x] = 0;
    __syncthreads();
    for (int i = threadIdx.x; i < cnt; i += 256) {
        unsigned v = pairs[s + i];
        lp[i] = v;
        atomicAdd(&h[v >> 25], 1);
    }
    __syncthreads();
    if (threadIdx.x < 128) ex[threadIdx.x] = h[threadIdx.x];
    __syncthreads();
    for (int off = 1; off < 128; off <<= 1) {
        int v = (threadIdx.x >= off && threadIdx.x < 128) ? ex[threadIdx.x - off] : 0;
        __syncthreads();
        if (threadIdx.x < 128) ex[threadIdx.x] += v;
        __syncthreads();
    }
    if (threadIdx.x < 128) {
        int e = ex[threadIdx.x] - h[threadIdx.x];
        cur[threadIdx.x] = e;
        int d = (b << BSHIFT) + threadIdx.x;
        if (d < nd) { offs[d] = s + e; counts[d] = h[threadIdx.x]; }
    }
    __syncthreads();
    for (int i = threadIdx.x; i < cnt; i += 256) {
        unsigned v = lp[i];
        int r = atomicAdd(&cur[v >> 25], 1);
        pairs[s + r] = v & 0x1FFFFFFu;  // now csr_src
    }
}

// ---- aggregate: one wave per dst; lane = output column ----
__global__ __launch_bounds__(256) void k_agg(
        const int* __restrict__ csr_src, const int* __restrict__ offs,
        const int* __restrict__ counts, const float* __restrict__ el,
        const float* __restrict__ er, const float* __restrict__ proj_src,
        const float* __restrict__ bias, float* __restrict__ out, int nd) {
    int wave = (blockIdx.x * 256 + threadIdx.x) >> 6;
    int lane = threadIdx.x & 63;
    if (wave >= nd) return;
    int d = wave;
    int h = lane >> 4;
    int start = offs[d], deg = counts[d];
    float er_h = er[d * 4 + h];

    // pass 1: online (m, den); lane j=(lane&15) strides edges by 16
    float m = -INFINITY, den = 0.f;
    for (int j = (lane & 15); j < deg; j += 16) {
        int s = csr_src[start + j];
        float x = el[s * 4 + h] + er_h;
        x = x > 0.f ? x : NEG_SLOPE * x;
        if (x > m) {
            den = den * __expf(m - x) + 1.f;
            m = x;
        } else {
            den += __expf(x - m);
        }
    }
#pragma unroll
    for (int off = 1; off < 16; off <<= 1) {
        float mo = __shfl_xor(m, off, 64);
        float dn = __shfl_xor(den, off, 64);
        float mn = fmaxf(m, mo);
        float sa = (m == -INFINITY) ? 0.f : __expf(m - mn);
        float sb = (mo == -INFINITY) ? 0.f : __expf(mo - mn);
        den = den * sa + dn * sb;
        m = mn;
    }
    float rden = (den > 0.f) ? 1.f / den : 0.f;

    // pass 2: all 64 lanes walk edges; coalesced 256B proj gather
    float acc = 0.f;
    int j = 0;
    for (; j + 2 <= deg; j += 2) {
        int s0 = csr_src[start + j];
        int s1 = csr_src[start + j + 1];
        float x0 = el[s0 * 4 + h] + er_h;
        float x1 = el[s1 * 4 + h] + er_h;
        float p0 = proj_src[(size_t)s0 * 64 + lane];
        float p1 = proj_src[(size_t)s1 * 64 + lane];
        x0 = x0 > 0.f ? x0 : NEG_SLOPE * x0;
        x1 = x1 > 0.f ? x1 : NEG_SLOPE * x1;
        acc += __expf(x0 - m) * rden * p0;
        acc += __expf(x1 - m) * rden * p1;
    }
    if (j < deg) {
        int s = csr_src[start + j];
        float x = el[s * 4 + h] + er_h;
        x = x > 0.f ? x : NEG_SLOPE * x;
        acc += __expf(x - m) * rden * proj_src[(size_t)s * 64 + lane];
    }

    out[(size_t)d * 64 + lane] = acc + bias[lane];
}

extern "C" void kernel_launch(void* const* d_in, const int* in_sizes, int n_in,
                              void* d_out, int out_size, void* d_ws, size_t ws_size,
                              hipStream_t stream) {
    const float* feat   = (const float*)d_in[0];
    const float* W      = (const float*)d_in[1];
    const float* attn_l = (const float*)d_in[2];
    const float* attn_r = (const float*)d_in[3];
    const float* bias   = (const float*)d_in[4];
    const int*   es     = (const int*)d_in[5];
    const int*   ed     = (const int*)d_in[6];

    const int HD      = in_sizes[2];            // 64
    const int in_f    = in_sizes[1] / HD;       // 128
    const int num_dst = out_size / HD;          // 50000
    const int num_tot = in_sizes[0] / in_f;     // 150000
    const int num_src = num_tot - num_dst;      // 100000
    const int E       = in_sizes[5];            // 1200000

    float* out = (float*)d_out;

    // ws layout (4-byte elements; sections multiple of 4 elems -> 16B aligned)
    float*    proj_src = (float*)d_ws;                         // num_src*64
    float*    el       = proj_src + (size_t)num_src * 64;      // num_src*4
    float*    er       = el + (size_t)num_src * 4;             // num_dst*4
    int*      counts   = (int*)(er + (size_t)num_dst * 4);     // num_dst
    int*      offs     = counts + num_dst;                     // num_dst
    int*      bukcnt   = offs + num_dst;                       // MAXBUK
    int*      bukstart = bukcnt + MAXBUK;                      // MAXBUK
    int*      bukcur   = bukstart + MAXBUK;                    // MAXBUK
    unsigned* pairs    = (unsigned*)(bukcur + MAXBUK);         // E (becomes csr_src)
    short*    Wb       = (short*)(pairs + E);                  // HD*in_f bf16

    const int NBUK = (num_dst + BMASK) >> BSHIFT;              // 391 (<= MAXBUK)

    hipMemsetAsync(bukcnt, 0, MAXBUK * sizeof(int), stream);

    k_wcvt<<<(HD * in_f + 255) / 256, 256, 0, stream>>>(W, Wb, HD * in_f);

    k_proj<<<(num_tot + 63) / 64, 256, 0, stream>>>(
        feat, Wb, attn_l, attn_r, proj_src, el, er, num_tot, num_dst);

    k_bhist<<<(E + 4095) / 4096, 256, 0, stream>>>(ed, bukcnt, E, NBUK);
    k_bscan<<<1, MAXBUK, 0, stream>>>(bukcnt, bukstart, bukcur, NBUK);
    k_bin<<<(E + 8191) / 8192, 256, 0, stream>>>(es, ed, bukcur, pairs, E, NBUK);
    k_fillb<<<NBUK, 256, 0, stream>>>(pairs, bukstart, bukcnt, offs, counts, num_dst);

    k_agg<<<(num_dst * 64 + 255) / 256, 256, 0, stream>>>(
        (const int*)pairs, offs, counts, el, er, proj_src, bias, out, num_dst);
}

// Round 5
// 176.453 us; speedup vs baseline: 7.1744x; 1.0813x over previous
//
#include <hip/hip_runtime.h>
#include <hip/hip_bf16.h>

// GAT conv: H=4 heads, D=16 (H*D = 64) — hardcoded per reference constants.
// feat: (N_tot, 128) f32, W: (64,128), attn_l/r: (4,16), bias: (64,)
// out: (NUM_DST, 4, 16) f32
//
// Pipeline: W->bf16 | MFMA projection (+fused el/er dots, bf16 proj store) |
// two-level CSR build (bucket hist -> scan -> bucket bin -> per-bucket fine
// fill, XCD-local scatters) | per-dst-wave single-pass flash-style aggregate.

#define NEG_SLOPE 0.2f
#define BSHIFT 7                 // bucket = dst >> 7 (128 dsts per bucket)
#define BMASK  127
#define MAXBUK 512               // supports num_dst <= 65536
#define BCAP   6144              // max edges per bucket (mean ~3070)

typedef __attribute__((ext_vector_type(8))) short bf16x8;  // 8 bf16 (4 VGPRs)
typedef __attribute__((ext_vector_type(4))) float f32x4;

__device__ __forceinline__ short f2bf(float f) {  // RNE f32->bf16 bits
    unsigned u = __float_as_uint(f);
    unsigned r = (u + 0x7fffu + ((u >> 16) & 1u)) >> 16;
    return (short)r;
}
__device__ __forceinline__ float bf2f(unsigned short u) {
    return __uint_as_float((unsigned)u << 16);
}

// ---- W fp32 -> bf16 (8192 elems) ----
__global__ void k_wcvt(const float* __restrict__ W, short* __restrict__ Wb, int n) {
    int t = blockIdx.x * blockDim.x + threadIdx.x;
    if (t < n) Wb[t] = f2bf(W[t]);
}

// ---- MFMA projection + fused attention dots ----
// block = 256 (4 waves); wave = 16 nodes x 64 outs, K=128 -> 16 MFMA 16x16x32.
__global__ __launch_bounds__(256) void k_proj(
        const float* __restrict__ feat, const short* __restrict__ Wb,
        const float* __restrict__ attn_l, const float* __restrict__ attn_r,
        unsigned short* __restrict__ projb, float* __restrict__ el, float* __restrict__ er,
        int num_tot, int num_dst) {
    const int lane = threadIdx.x & 63;
    const int wv = threadIdx.x >> 6;
    const int lr = lane & 15;
    const int lg = lane >> 4;
    const int nbase = blockIdx.x * 64 + wv * 16;

    int arow = nbase + lr;
    if (arow >= num_tot) arow = num_tot - 1;  // clamp; stores are guarded
    const float* ap = feat + (size_t)arow * 128 + lg * 8;
    bf16x8 afrag[4];
#pragma unroll
    for (int c = 0; c < 4; c++) {
        float4 x = *(const float4*)(ap + c * 32);
        float4 y = *(const float4*)(ap + c * 32 + 4);
        bf16x8 t;
        t[0] = f2bf(x.x); t[1] = f2bf(x.y); t[2] = f2bf(x.z); t[3] = f2bf(x.w);
        t[4] = f2bf(y.x); t[5] = f2bf(y.y); t[6] = f2bf(y.z); t[7] = f2bf(y.w);
        afrag[c] = t;
    }

    f32x4 acc[4];
#pragma unroll
    for (int h = 0; h < 4; h++) acc[h] = f32x4{0.f, 0.f, 0.f, 0.f};
#pragma unroll
    for (int h = 0; h < 4; h++) {
        const short* bp = Wb + (h * 16 + lr) * 128 + lg * 8;
#pragma unroll
        for (int c = 0; c < 4; c++) {
            bf16x8 b = *(const bf16x8*)(bp + c * 32);
            acc[h] = __builtin_amdgcn_mfma_f32_16x16x32_bf16(afrag[c], b, acc[h], 0, 0, 0);
        }
    }

    // proj store (src rows only), bf16
    const int rbase = nbase + lg * 4;
#pragma unroll
    for (int r = 0; r < 4; r++) {
        int n = rbase + r;
        if (n >= num_dst && n < num_tot) {
            unsigned short* prow = projb + (size_t)(n - num_dst) * 64;
#pragma unroll
            for (int h = 0; h < 4; h++) prow[h * 16 + lr] = (unsigned short)f2bf(acc[h][r]);
        }
    }

    // fused el/er: row-sum of acc[h] * attn[h][col] over the 16-lane col group
#pragma unroll
    for (int h = 0; h < 4; h++) {
        float al = attn_l[h * 16 + lr];
        float ar = attn_r[h * 16 + lr];
#pragma unroll
        for (int r = 0; r < 4; r++) {
            int n = rbase + r;
            float v = acc[h][r] * ((n < num_dst) ? ar : al);
            v += __shfl_xor(v, 1);
            v += __shfl_xor(v, 2);
            v += __shfl_xor(v, 4);
            v += __shfl_xor(v, 8);
            if (lr == h) {
                if (n < num_dst) er[(size_t)n * 4 + h] = v;
                else if (n < num_tot) el[(size_t)(n - num_dst) * 4 + h] = v;
            }
        }
    }
}

// ---- bucket histogram: LDS pre-aggregation ----
__global__ __launch_bounds__(256) void k_bhist(const int* __restrict__ ed,
                                               int* __restrict__ bukcnt, int E, int nbuk) {
    __shared__ int h[MAXBUK];
    for (int i = threadIdx.x; i < MAXBUK; i += 256) h[i] = 0;
    __syncthreads();
    int base = blockIdx.x * 4096;
#pragma unroll
    for (int i = 0; i < 16; i++) {
        int idx = base + threadIdx.x + i * 256;
        if (idx < E) atomicAdd(&h[ed[idx] >> BSHIFT], 1);
    }
    __syncthreads();
    for (int i = threadIdx.x; i < nbuk; i += 256)
        if (h[i]) atomicAdd(&bukcnt[i], h[i]);
}

// ---- exclusive scan of bucket counts (nbuk <= 512), init cursors ----
__global__ __launch_bounds__(512) void k_bscan(const int* __restrict__ bukcnt,
                                               int* __restrict__ bukstart,
                                               int* __restrict__ bukcur, int nbuk) {
    __shared__ int sh[MAXBUK];
    int tid = threadIdx.x;
    int c = (tid < nbuk) ? bukcnt[tid] : 0;
    sh[tid] = c;
    __syncthreads();
    for (int off = 1; off < MAXBUK; off <<= 1) {
        int v = (tid >= off) ? sh[tid - off] : 0;
        __syncthreads();
        sh[tid] += v;
        __syncthreads();
    }
    int ex = sh[tid] - c;
    if (tid < nbuk) { bukstart[tid] = ex; bukcur[tid] = ex; }
}

// ---- coarse bin: scatter packed (src | dloc<<25) into bucket runs ----
__global__ __launch_bounds__(256) void k_bin(const int* __restrict__ es,
                                             const int* __restrict__ ed,
                                             int* __restrict__ bukcur,
                                             unsigned* __restrict__ pairs, int E, int nbuk) {
    __shared__ int h[MAXBUK];
    __shared__ int cur[MAXBUK];
    for (int i = threadIdx.x; i < MAXBUK; i += 256) h[i] = 0;
    __syncthreads();
    int base = blockIdx.x * 8192;
#pragma unroll
    for (int i = 0; i < 32; i++) {
        int idx = base + threadIdx.x + i * 256;
        if (idx < E) atomicAdd(&h[ed[idx] >> BSHIFT], 1);
    }
    __syncthreads();
    for (int i = threadIdx.x; i < nbuk; i += 256)
        cur[i] = h[i] ? atomicAdd(&bukcur[i], h[i]) : 0;
    __syncthreads();
#pragma unroll
    for (int i = 0; i < 32; i++) {
        int idx = base + threadIdx.x + i * 256;
        if (idx < E) {
            int d = ed[idx];
            int pos = atomicAdd(&cur[d >> BSHIFT], 1);
            pairs[pos] = (unsigned)es[idx] | ((unsigned)(d & BMASK) << 25);
        }
    }
}

// ---- fine fill: one block per bucket; LDS-staged in-place permute to CSR;
//      also emits offs[] and counts[]. ----
__global__ __launch_bounds__(256) void k_fillb(unsigned* __restrict__ pairs,
                                               const int* __restrict__ bukstart,
                                               const int* __restrict__ bukcnt,
                                               int* __restrict__ offs,
                                               int* __restrict__ counts, int nd) {
    __shared__ unsigned lp[BCAP];
    __shared__ int h[128], ex[128], cur[128];
    int b = blockIdx.x;
    int s = bukstart[b];
    int cnt = bukcnt[b];
    if (cnt > BCAP) cnt = BCAP;  // statistically impossible; guard anyway
    if (threadIdx.x < 128) h[threadIdx.x] = 0;
    __syncthreads();
    for (int i = threadIdx.x; i < cnt; i += 256) {
        unsigned v = pairs[s + i];
        lp[i] = v;
        atomicAdd(&h[v >> 25], 1);
    }
    __syncthreads();
    if (threadIdx.x < 128) ex[threadIdx.x] = h[threadIdx.x];
    __syncthreads();
    for (int off = 1; off < 128; off <<= 1) {
        int v = (threadIdx.x >= off && threadIdx.x < 128) ? ex[threadIdx.x - off] : 0;
        __syncthreads();
        if (threadIdx.x < 128) ex[threadIdx.x] += v;
        __syncthreads();
    }
    if (threadIdx.x < 128) {
        int e = ex[threadIdx.x] - h[threadIdx.x];
        cur[threadIdx.x] = e;
        int d = (b << BSHIFT) + threadIdx.x;
        if (d < nd) { offs[d] = s + e; counts[d] = h[threadIdx.x]; }
    }
    __syncthreads();
    for (int i = threadIdx.x; i < cnt; i += 256) {
        unsigned v = lp[i];
        int r = atomicAdd(&cur[v >> 25], 1);
        pairs[s + r] = v & 0x1FFFFFFu;  // now csr_src
    }
}

// ---- aggregate: one wave per dst; single-pass flash-style online softmax.
// lane roles: coefficient for (edge j=lane&15, head h=lane>>4); accumulator
// for output column c=lane. Chunks of 16 edges. ----
__global__ __launch_bounds__(256) void k_agg(
        const int* __restrict__ csr_src, const int* __restrict__ offs,
        const int* __restrict__ counts, const float* __restrict__ el,
        const float* __restrict__ er, const unsigned short* __restrict__ projb,
        const float* __restrict__ bias, float* __restrict__ out, int nd) {
    int wave = (blockIdx.x * 256 + threadIdx.x) >> 6;
    int lane = threadIdx.x & 63;
    if (wave >= nd) return;
    int d = wave;
    int j = lane & 15, h = lane >> 4;
    int start = offs[d], deg = counts[d];
    float er_h = er[d * 4 + h];
    float bias_c = bias[lane];
    const int gb = lane & 48;

    float m = -INFINITY, den = 0.f, acc = 0.f;
    for (int base = 0; base < deg; base += 16) {
        int cend = deg - base;
        if (cend > 16) cend = 16;
        int sidx = 0;
        float x = -INFINITY;
        if (j < cend) {
            sidx = csr_src[start + base + j];
            float t = el[sidx * 4 + h] + er_h;
            x = t > 0.f ? t : NEG_SLOPE * t;
        }
        // chunk max within the 16-lane head group
        float pm = x;
        pm = fmaxf(pm, __shfl_xor(pm, 1));
        pm = fmaxf(pm, __shfl_xor(pm, 2));
        pm = fmaxf(pm, __shfl_xor(pm, 4));
        pm = fmaxf(pm, __shfl_xor(pm, 8));
        float mn = fmaxf(m, pm);          // chunk nonempty -> mn finite
        float sc = __expf(m - mn);        // first chunk: exp(-inf)=0
        den *= sc;
        acc *= sc;
        m = mn;
        float w = __expf(x - m);          // invalid lanes: x=-inf -> 0
        den += w;

        if (cend == 16) {
#pragma unroll
            for (int j2 = 0; j2 < 16; j2++) {
                float coef = __shfl(w, gb | j2);
                int s2 = __shfl(sidx, j2);
                acc += coef * bf2f(projb[(size_t)s2 * 64 + lane]);
            }
        } else {
            for (int j2 = 0; j2 < cend; j2++) {
                float coef = __shfl(w, gb | j2);
                int s2 = __shfl(sidx, j2);
                acc += coef * bf2f(projb[(size_t)s2 * 64 + lane]);
            }
        }
    }

    // total den over the 16-lane group
    den += __shfl_xor(den, 1);
    den += __shfl_xor(den, 2);
    den += __shfl_xor(den, 4);
    den += __shfl_xor(den, 8);
    float rden = (den > 0.f) ? 1.f / den : 0.f;

    out[(size_t)d * 64 + lane] = acc * rden + bias_c;
}

extern "C" void kernel_launch(void* const* d_in, const int* in_sizes, int n_in,
                              void* d_out, int out_size, void* d_ws, size_t ws_size,
                              hipStream_t stream) {
    const float* feat   = (const float*)d_in[0];
    const float* W      = (const float*)d_in[1];
    const float* attn_l = (const float*)d_in[2];
    const float* attn_r = (const float*)d_in[3];
    const float* bias   = (const float*)d_in[4];
    const int*   es     = (const int*)d_in[5];
    const int*   ed     = (const int*)d_in[6];

    const int HD      = in_sizes[2];            // 64
    const int in_f    = in_sizes[1] / HD;       // 128
    const int num_dst = out_size / HD;          // 50000
    const int num_tot = in_sizes[0] / in_f;     // 150000
    const int num_src = num_tot - num_dst;      // 100000
    const int E       = in_sizes[5];            // 1200000

    float* out = (float*)d_out;

    // ws layout (sections 16B aligned)
    unsigned short* projb = (unsigned short*)d_ws;             // num_src*64 bf16
    float*    el       = (float*)(projb + (size_t)num_src * 64); // num_src*4
    float*    er       = el + (size_t)num_src * 4;             // num_dst*4
    int*      counts   = (int*)(er + (size_t)num_dst * 4);     // num_dst
    int*      offs     = counts + num_dst;                     // num_dst
    int*      bukcnt   = offs + num_dst;                       // MAXBUK
    int*      bukstart = bukcnt + MAXBUK;                      // MAXBUK
    int*      bukcur   = bukstart + MAXBUK;                    // MAXBUK
    unsigned* pairs    = (unsigned*)(bukcur + MAXBUK);         // E (becomes csr_src)
    short*    Wb       = (short*)(pairs + E);                  // HD*in_f bf16

    const int NBUK = (num_dst + BMASK) >> BSHIFT;              // 391 (<= MAXBUK)

    hipMemsetAsync(bukcnt, 0, MAXBUK * sizeof(int), stream);

    k_wcvt<<<(HD * in_f + 255) / 256, 256, 0, stream>>>(W, Wb, HD * in_f);

    k_proj<<<(num_tot + 63) / 64, 256, 0, stream>>>(
        feat, Wb, attn_l, attn_r, projb, el, er, num_tot, num_dst);

    k_bhist<<<(E + 4095) / 4096, 256, 0, stream>>>(ed, bukcnt, E, NBUK);
    k_bscan<<<1, MAXBUK, 0, stream>>>(bukcnt, bukstart, bukcur, NBUK);
    k_bin<<<(E + 8191) / 8192, 256, 0, stream>>>(es, ed, bukcur, pairs, E, NBUK);
    k_fillb<<<NBUK, 256, 0, stream>>>(pairs, bukstart, bukcnt, offs, counts, num_dst);

    k_agg<<<(num_dst * 64 + 255) / 256, 256, 0, stream>>>(
        (const int*)pairs, offs, counts, el, er, projb, bias, out, num_dst);
}

// Round 6
// 137.043 us; speedup vs baseline: 9.2375x; 1.2876x over previous
//
#include <hip/hip_runtime.h>
#include <hip/hip_bf16.h>

// GAT conv: H=4 heads, D=16 (H*D = 64) — hardcoded per reference constants.
// feat: (N_tot, 128) f32, W: (64,128), attn_l/r: (4,16), bias: (64,)
// out: (NUM_DST, 4, 16) f32
//
// Pipeline (6 dispatches): memset | bhist(+W->bf16) | bscan | proj+bin (one
// grid) | fillb | agg. CSR built via two-level XCD-local binning; aggregate is
// a per-dst-wave streaming softmax (shift-invariant, no running max needed —
// inputs bounded; safety clamp at 60) with dword bf16-pair gathers.

#define NEG_SLOPE 0.2f
#define BSHIFT 7                 // bucket = dst >> 7 (128 dsts per bucket)
#define BMASK  127
#define MAXBUK 512               // supports num_dst <= 65536
#define BCAP   6144              // max edges per bucket (mean ~3070)

typedef __attribute__((ext_vector_type(8))) short bf16x8;  // 8 bf16 (4 VGPRs)
typedef __attribute__((ext_vector_type(4))) float f32x4;

__device__ __forceinline__ short f2bf(float f) {  // RNE f32->bf16 bits
    unsigned u = __float_as_uint(f);
    unsigned r = (u + 0x7fffu + ((u >> 16) & 1u)) >> 16;
    return (short)r;
}

// ---- bucket histogram (LDS pre-aggregation) + W fp32->bf16 (first 8 blocks) ----
__global__ __launch_bounds__(256) void k_bhist(const int* __restrict__ ed,
                                               int* __restrict__ bukcnt,
                                               const float* __restrict__ W,
                                               short* __restrict__ Wb, int nW,
                                               int E, int nbuk) {
    if (blockIdx.x < 8) {
#pragma unroll
        for (int i = 0; i < 4; i++) {
            int idx = blockIdx.x * 1024 + i * 256 + threadIdx.x;
            if (idx < nW) Wb[idx] = f2bf(W[idx]);
        }
    }
    __shared__ int h[MAXBUK];
    for (int i = threadIdx.x; i < MAXBUK; i += 256) h[i] = 0;
    __syncthreads();
    int base = blockIdx.x * 4096;
#pragma unroll
    for (int i = 0; i < 16; i++) {
        int idx = base + threadIdx.x + i * 256;
        if (idx < E) atomicAdd(&h[ed[idx] >> BSHIFT], 1);
    }
    __syncthreads();
    for (int i = threadIdx.x; i < nbuk; i += 256)
        if (h[i]) atomicAdd(&bukcnt[i], h[i]);
}

// ---- exclusive scan of bucket counts (nbuk <= 512), init cursors ----
__global__ __launch_bounds__(512) void k_bscan(const int* __restrict__ bukcnt,
                                               int* __restrict__ bukstart,
                                               int* __restrict__ bukcur, int nbuk) {
    __shared__ int sh[MAXBUK];
    int tid = threadIdx.x;
    int c = (tid < nbuk) ? bukcnt[tid] : 0;
    sh[tid] = c;
    __syncthreads();
    for (int off = 1; off < MAXBUK; off <<= 1) {
        int v = (tid >= off) ? sh[tid - off] : 0;
        __syncthreads();
        sh[tid] += v;
        __syncthreads();
    }
    int ex = sh[tid] - c;
    if (tid < nbuk) { bukstart[tid] = ex; bukcur[tid] = ex; }
}

// ---- merged dispatch: MFMA projection (+fused el/er) | coarse bin ----
// blocks [0, projB): proj.  blocks [projB, projB+binB): bin.
__global__ __launch_bounds__(256) void k_proj_bin(
        const float* __restrict__ feat, const short* __restrict__ Wb,
        const float* __restrict__ attn_l, const float* __restrict__ attn_r,
        unsigned short* __restrict__ projb, float* __restrict__ el, float* __restrict__ er,
        int num_tot, int num_dst, int projB,
        const int* __restrict__ es, const int* __restrict__ ed,
        int* __restrict__ bukcur, unsigned* __restrict__ pairs, int E, int nbuk) {
    __shared__ int h[MAXBUK];
    __shared__ int cur[MAXBUK];
    if ((int)blockIdx.x < projB) {
        // ---- projection: wave = 16 nodes x 64 outs, K=128 -> 16 MFMA 16x16x32
        const int lane = threadIdx.x & 63;
        const int wv = threadIdx.x >> 6;
        const int lr = lane & 15;
        const int lg = lane >> 4;
        const int nbase = blockIdx.x * 64 + wv * 16;

        int arow = nbase + lr;
        if (arow >= num_tot) arow = num_tot - 1;  // clamp; stores are guarded
        const float* ap = feat + (size_t)arow * 128 + lg * 8;
        bf16x8 afrag[4];
#pragma unroll
        for (int c = 0; c < 4; c++) {
            float4 x = *(const float4*)(ap + c * 32);
            float4 y = *(const float4*)(ap + c * 32 + 4);
            bf16x8 t;
            t[0] = f2bf(x.x); t[1] = f2bf(x.y); t[2] = f2bf(x.z); t[3] = f2bf(x.w);
            t[4] = f2bf(y.x); t[5] = f2bf(y.y); t[6] = f2bf(y.z); t[7] = f2bf(y.w);
            afrag[c] = t;
        }

        f32x4 acc[4];
#pragma unroll
        for (int hh = 0; hh < 4; hh++) acc[hh] = f32x4{0.f, 0.f, 0.f, 0.f};
#pragma unroll
        for (int hh = 0; hh < 4; hh++) {
            const short* bp = Wb + (hh * 16 + lr) * 128 + lg * 8;
#pragma unroll
            for (int c = 0; c < 4; c++) {
                bf16x8 b = *(const bf16x8*)(bp + c * 32);
                acc[hh] = __builtin_amdgcn_mfma_f32_16x16x32_bf16(afrag[c], b, acc[hh], 0, 0, 0);
            }
        }

        const int rbase = nbase + lg * 4;
#pragma unroll
        for (int r = 0; r < 4; r++) {
            int n = rbase + r;
            if (n >= num_dst && n < num_tot) {
                unsigned short* prow = projb + (size_t)(n - num_dst) * 64;
#pragma unroll
                for (int hh = 0; hh < 4; hh++) prow[hh * 16 + lr] = (unsigned short)f2bf(acc[hh][r]);
            }
        }

#pragma unroll
        for (int hh = 0; hh < 4; hh++) {
            float al = attn_l[hh * 16 + lr];
            float ar = attn_r[hh * 16 + lr];
#pragma unroll
            for (int r = 0; r < 4; r++) {
                int n = rbase + r;
                float v = acc[hh][r] * ((n < num_dst) ? ar : al);
                v += __shfl_xor(v, 1);
                v += __shfl_xor(v, 2);
                v += __shfl_xor(v, 4);
                v += __shfl_xor(v, 8);
                if (lr == hh) {
                    if (n < num_dst) er[(size_t)n * 4 + hh] = v;
                    else if (n < num_tot) el[(size_t)(n - num_dst) * 4 + hh] = v;
                }
            }
        }
    } else {
        // ---- coarse bin: scatter packed (src | dloc<<25) into bucket runs
        int bb = (int)blockIdx.x - projB;
        for (int i = threadIdx.x; i < MAXBUK; i += 256) h[i] = 0;
        __syncthreads();
        int base = bb * 8192;
#pragma unroll
        for (int i = 0; i < 32; i++) {
            int idx = base + threadIdx.x + i * 256;
            if (idx < E) atomicAdd(&h[ed[idx] >> BSHIFT], 1);
        }
        __syncthreads();
        for (int i = threadIdx.x; i < nbuk; i += 256)
            cur[i] = h[i] ? atomicAdd(&bukcur[i], h[i]) : 0;
        __syncthreads();
#pragma unroll
        for (int i = 0; i < 32; i++) {
            int idx = base + threadIdx.x + i * 256;
            if (idx < E) {
                int d = ed[idx];
                int pos = atomicAdd(&cur[d >> BSHIFT], 1);
                pairs[pos] = (unsigned)es[idx] | ((unsigned)(d & BMASK) << 25);
            }
        }
    }
}

// ---- fine fill: one block per bucket; LDS-staged in-place permute to CSR;
//      also emits offs[] and counts[]. ----
__global__ __launch_bounds__(256) void k_fillb(unsigned* __restrict__ pairs,
                                               const int* __restrict__ bukstart,
                                               const int* __restrict__ bukcnt,
                                               int* __restrict__ offs,
                                               int* __restrict__ counts, int nd) {
    __shared__ unsigned lp[BCAP];
    __shared__ int h[128], ex[128], cur[128];
    int b = blockIdx.x;
    int s = bukstart[b];
    int cnt = bukcnt[b];
    if (cnt > BCAP) cnt = BCAP;  // statistically impossible; guard anyway
    if (threadIdx.x < 128) h[threadIdx.x] = 0;
    __syncthreads();
    for (int i = threadIdx.x; i < cnt; i += 256) {
        unsigned v = pairs[s + i];
        lp[i] = v;
        atomicAdd(&h[v >> 25], 1);
    }
    __syncthreads();
    if (threadIdx.x < 128) ex[threadIdx.x] = h[threadIdx.x];
    __syncthreads();
    for (int off = 1; off < 128; off <<= 1) {
        int v = (threadIdx.x >= off && threadIdx.x < 128) ? ex[threadIdx.x - off] : 0;
        __syncthreads();
        if (threadIdx.x < 128) ex[threadIdx.x] += v;
        __syncthreads();
    }
    if (threadIdx.x < 128) {
        int e = ex[threadIdx.x] - h[threadIdx.x];
        cur[threadIdx.x] = e;
        int d = (b << BSHIFT) + threadIdx.x;
        if (d < nd) { offs[d] = s + e; counts[d] = h[threadIdx.x]; }
    }
    __syncthreads();
    for (int i = threadIdx.x; i < cnt; i += 256) {
        unsigned v = lp[i];
        int r = atomicAdd(&cur[v >> 25], 1);
        pairs[s + r] = v & 0x1FFFFFFu;  // now csr_src
    }
}

// ---- aggregate: one wave per dst; streaming softmax (no running max — shift
// invariant; inputs bounded, clamp 60 inactive). Coef lanes (h=lane>>4,
// j=lane&15); accumulate 2 edges in parallel across wave halves, each lane
// owning a bf16 column PAIR (dword gather). ----
__global__ __launch_bounds__(256) void k_agg(
        const int* __restrict__ csr_src, const int* __restrict__ offs,
        const int* __restrict__ counts, const float* __restrict__ el,
        const float* __restrict__ er, const unsigned short* __restrict__ projb,
        const float* __restrict__ bias, float* __restrict__ out, int nd) {
    int wave = (blockIdx.x * 256 + threadIdx.x) >> 6;
    int lane = threadIdx.x & 63;
    if (wave >= nd) return;
    int d = wave;
    int j = lane & 15, h = lane >> 4;
    int cp = lane & 31, half = lane >> 5;
    int hp16 = (cp >> 3) << 4;          // base lane of head group owning cols 2cp,2cp+1
    int start = offs[d], deg = counts[d];
    float er_h = er[d * 4 + h];

    float den = 0.f, acc0 = 0.f, acc1 = 0.f;
    for (int base = 0; base < deg; base += 16) {
        int cend = deg - base;
        if (cend > 16) cend = 16;
        int sidx = 0;
        float w = 0.f;
        if (j < cend) {
            sidx = csr_src[start + base + j];
            float t = el[sidx * 4 + h] + er_h;
            t = t > 0.f ? t : NEG_SLOPE * t;
            w = __expf(fminf(t, 60.f));
        }
        den += w;
        if (cend == 16) {
#pragma unroll
            for (int t8 = 0; t8 < 8; t8++) {
                int e = 2 * t8 + half;
                int s2 = __shfl(sidx, e);
                float w2 = __shfl(w, hp16 + e);
                unsigned pv = *(const unsigned*)(projb + (size_t)s2 * 64 + cp * 2);
                acc0 += w2 * __uint_as_float(pv << 16);
                acc1 += w2 * __uint_as_float(pv & 0xffff0000u);
            }
        } else {
            int steps = (cend + 1) >> 1;
            for (int t8 = 0; t8 < steps; t8++) {
                int e = 2 * t8 + half;          // may equal cend: w2=0, s2=0 (safe)
                int s2 = __shfl(sidx, e);
                float w2 = __shfl(w, hp16 + e);
                unsigned pv = *(const unsigned*)(projb + (size_t)s2 * 64 + cp * 2);
                acc0 += w2 * __uint_as_float(pv << 16);
                acc1 += w2 * __uint_as_float(pv & 0xffff0000u);
            }
        }
    }

    // per-head denominator (sum over the 16 j-lanes of each head group)
    den += __shfl_xor(den, 1);
    den += __shfl_xor(den, 2);
    den += __shfl_xor(den, 4);
    den += __shfl_xor(den, 8);
    float den_h = __shfl(den, hp16);

    // combine the two edge-halves
    acc0 += __shfl_xor(acc0, 32);
    acc1 += __shfl_xor(acc1, 32);

    if (half == 0) {
        float rden = den_h > 0.f ? 1.f / den_h : 0.f;
        float2 o;
        o.x = acc0 * rden + bias[cp * 2];
        o.y = acc1 * rden + bias[cp * 2 + 1];
        *(float2*)&out[(size_t)d * 64 + cp * 2] = o;
    }
}

extern "C" void kernel_launch(void* const* d_in, const int* in_sizes, int n_in,
                              void* d_out, int out_size, void* d_ws, size_t ws_size,
                              hipStream_t stream) {
    const float* feat   = (const float*)d_in[0];
    const float* W      = (const float*)d_in[1];
    const float* attn_l = (const float*)d_in[2];
    const float* attn_r = (const float*)d_in[3];
    const float* bias   = (const float*)d_in[4];
    const int*   es     = (const int*)d_in[5];
    const int*   ed     = (const int*)d_in[6];

    const int HD      = in_sizes[2];            // 64
    const int in_f    = in_sizes[1] / HD;       // 128
    const int num_dst = out_size / HD;          // 50000
    const int num_tot = in_sizes[0] / in_f;     // 150000
    const int num_src = num_tot - num_dst;      // 100000
    const int E       = in_sizes[5];            // 1200000

    float* out = (float*)d_out;

    // ws layout (all sections multiples of 4 dwords -> 16B aligned)
    unsigned short* projb = (unsigned short*)d_ws;               // num_src*64 bf16
    float*    el       = (float*)(projb + (size_t)num_src * 64); // num_src*4
    float*    er       = el + (size_t)num_src * 4;               // num_dst*4
    int*      counts   = (int*)(er + (size_t)num_dst * 4);       // num_dst
    int*      offs     = counts + num_dst;                       // num_dst
    int*      bukcnt   = offs + num_dst;                         // MAXBUK
    int*      bukstart = bukcnt + MAXBUK;                        // MAXBUK
    int*      bukcur   = bukstart + MAXBUK;                      // MAXBUK
    unsigned* pairs    = (unsigned*)(bukcur + MAXBUK);           // E (becomes csr_src)
    short*    Wb       = (short*)(pairs + E);                    // HD*in_f bf16

    const int NBUK  = (num_dst + BMASK) >> BSHIFT;               // 391 (<= MAXBUK)
    const int projB = (num_tot + 63) / 64;                       // 2344
    const int binB  = (E + 8191) / 8192;                         // 147

    hipMemsetAsync(bukcnt, 0, MAXBUK * sizeof(int), stream);

    k_bhist<<<(E + 4095) / 4096, 256, 0, stream>>>(ed, bukcnt, W, Wb, HD * in_f, E, NBUK);
    k_bscan<<<1, MAXBUK, 0, stream>>>(bukcnt, bukstart, bukcur, NBUK);

    k_proj_bin<<<projB + binB, 256, 0, stream>>>(
        feat, Wb, attn_l, attn_r, projb, el, er, num_tot, num_dst, projB,
        es, ed, bukcur, pairs, E, NBUK);

    k_fillb<<<NBUK, 256, 0, stream>>>(pairs, bukstart, bukcnt, offs, counts, num_dst);

    k_agg<<<(num_dst * 64 + 255) / 256, 256, 0, stream>>>(
        (const int*)pairs, offs, counts, el, er, projb, bias, out, num_dst);
}

// Round 7
// 135.116 us; speedup vs baseline: 9.3693x; 1.0143x over previous
//
#include <hip/hip_runtime.h>
#include <hip/hip_bf16.h>

// GAT conv: H=4 heads, D=16 (H*D = 64) — hardcoded per reference constants.
// feat: (N_tot, 128) f32, W: (64,128), attn_l/r: (4,16), bias: (64,)
// out: (NUM_DST, 4, 16) f32
//
// Pipeline (6 dispatches): memset | bhist(+W->bf16) | bscan | proj+bin (one
// grid) | fillb | agg. Projection stages the 64-row feat tile through LDS
// (coalesced f32 loads -> bf16 -> swizzled ds_write_b128; a-frags via 4
// conflict-free ds_read_b128). CSR via two-level XCD-local binning; aggregate
// is a per-dst-wave streaming softmax with dword bf16-pair gathers.

#define NEG_SLOPE 0.2f
#define BSHIFT 7                 // bucket = dst >> 7 (128 dsts per bucket)
#define BMASK  127
#define MAXBUK 512               // supports num_dst <= 65536
#define BCAP   6144              // max edges per bucket (mean ~3070)

typedef __attribute__((ext_vector_type(8))) short bf16x8;  // 8 bf16 (4 VGPRs)
typedef __attribute__((ext_vector_type(4))) float f32x4;

__device__ __forceinline__ short f2bf(float f) {  // RNE f32->bf16 bits
    unsigned u = __float_as_uint(f);
    unsigned r = (u + 0x7fffu + ((u >> 16) & 1u)) >> 16;
    return (short)r;
}

// ---- bucket histogram (LDS pre-aggregation) + W fp32->bf16 (first 8 blocks) ----
__global__ __launch_bounds__(256) void k_bhist(const int* __restrict__ ed,
                                               int* __restrict__ bukcnt,
                                               const float* __restrict__ W,
                                               short* __restrict__ Wb, int nW,
                                               int E, int nbuk) {
    if (blockIdx.x < 8) {
#pragma unroll
        for (int i = 0; i < 4; i++) {
            int idx = blockIdx.x * 1024 + i * 256 + threadIdx.x;
            if (idx < nW) Wb[idx] = f2bf(W[idx]);
        }
    }
    __shared__ int h[MAXBUK];
    for (int i = threadIdx.x; i < MAXBUK; i += 256) h[i] = 0;
    __syncthreads();
    int base = blockIdx.x * 4096;
#pragma unroll
    for (int i = 0; i < 16; i++) {
        int idx = base + threadIdx.x + i * 256;
        if (idx < E) atomicAdd(&h[ed[idx] >> BSHIFT], 1);
    }
    __syncthreads();
    for (int i = threadIdx.x; i < nbuk; i += 256)
        if (h[i]) atomicAdd(&bukcnt[i], h[i]);
}

// ---- exclusive scan of bucket counts (nbuk <= 512), init cursors ----
__global__ __launch_bounds__(512) void k_bscan(const int* __restrict__ bukcnt,
                                               int* __restrict__ bukstart,
                                               int* __restrict__ bukcur, int nbuk) {
    __shared__ int sh[MAXBUK];
    int tid = threadIdx.x;
    int c = (tid < nbuk) ? bukcnt[tid] : 0;
    sh[tid] = c;
    __syncthreads();
    for (int off = 1; off < MAXBUK; off <<= 1) {
        int v = (tid >= off) ? sh[tid - off] : 0;
        __syncthreads();
        sh[tid] += v;
        __syncthreads();
    }
    int ex = sh[tid] - c;
    if (tid < nbuk) { bukstart[tid] = ex; bukcur[tid] = ex; }
}

// ---- merged dispatch: MFMA projection (+fused el/er) | coarse bin ----
// blocks [0, projB): proj.  blocks [projB, projB+binB): bin.
__global__ __launch_bounds__(256) void k_proj_bin(
        const float* __restrict__ feat, const short* __restrict__ Wb,
        const float* __restrict__ attn_l, const float* __restrict__ attn_r,
        unsigned short* __restrict__ projb, float* __restrict__ el, float* __restrict__ er,
        int num_tot, int num_dst, int projB,
        const int* __restrict__ es, const int* __restrict__ ed,
        int* __restrict__ bukcur, unsigned* __restrict__ pairs, int E, int nbuk) {
    __shared__ __align__(16) unsigned short fs[64 * 128];  // 16 KB bf16 A-tile (swizzled)
    __shared__ int h[MAXBUK];
    __shared__ int cur[MAXBUK];
    if ((int)blockIdx.x < projB) {
        const int tid = threadIdx.x;
        const int nblk = blockIdx.x * 64;

        // ---- stage feat tile: coalesced f32 loads -> bf16 -> swizzled LDS.
        // iteration covers 16 rows (256 thr x 8 elems); slot' = slot ^ (row&15).
#pragma unroll
        for (int it = 0; it < 4; it++) {
            int flat = it * 2048 + tid * 8;
            int row = flat >> 7;          // 0..63
            int col = flat & 127;         // multiple of 8
            int grow = nblk + row;
            if (grow >= num_tot) grow = num_tot - 1;  // clamp (outputs guarded)
            const float4* src = (const float4*)(feat + (size_t)grow * 128 + col);
            float4 x = src[0], y = src[1];
            bf16x8 t;
            t[0] = f2bf(x.x); t[1] = f2bf(x.y); t[2] = f2bf(x.z); t[3] = f2bf(x.w);
            t[4] = f2bf(y.x); t[5] = f2bf(y.y); t[6] = f2bf(y.z); t[7] = f2bf(y.w);
            int slot = col >> 3;          // 0..15 (16B units)
            *(bf16x8*)&fs[row * 128 + ((slot ^ (row & 15)) << 3)] = t;
        }
        __syncthreads();

        // ---- projection: wave = 16 nodes x 64 outs, K=128 -> 16 MFMA 16x16x32
        const int lane = threadIdx.x & 63;
        const int wv = threadIdx.x >> 6;
        const int lr = lane & 15;
        const int lg = lane >> 4;
        const int nbase = nblk + wv * 16;
        const int srow = wv * 16 + lr;

        bf16x8 afrag[4];
#pragma unroll
        for (int c = 0; c < 4; c++) {
            int slot = c * 4 + lg;        // col chunk (lg*8 + c*32)/8
            afrag[c] = *(const bf16x8*)&fs[srow * 128 + ((slot ^ (lr & 15)) << 3)];
        }

        f32x4 acc[4];
#pragma unroll
        for (int hh = 0; hh < 4; hh++) acc[hh] = f32x4{0.f, 0.f, 0.f, 0.f};
#pragma unroll
        for (int hh = 0; hh < 4; hh++) {
            const short* bp = Wb + (hh * 16 + lr) * 128 + lg * 8;
#pragma unroll
            for (int c = 0; c < 4; c++) {
                bf16x8 b = *(const bf16x8*)(bp + c * 32);
                acc[hh] = __builtin_amdgcn_mfma_f32_16x16x32_bf16(afrag[c], b, acc[hh], 0, 0, 0);
            }
        }

        const int rbase = nbase + lg * 4;
#pragma unroll
        for (int r = 0; r < 4; r++) {
            int n = rbase + r;
            if (n >= num_dst && n < num_tot) {
                unsigned short* prow = projb + (size_t)(n - num_dst) * 64;
#pragma unroll
                for (int hh = 0; hh < 4; hh++) prow[hh * 16 + lr] = (unsigned short)f2bf(acc[hh][r]);
            }
        }

#pragma unroll
        for (int hh = 0; hh < 4; hh++) {
            float al = attn_l[hh * 16 + lr];
            float ar = attn_r[hh * 16 + lr];
#pragma unroll
            for (int r = 0; r < 4; r++) {
                int n = rbase + r;
                float v = acc[hh][r] * ((n < num_dst) ? ar : al);
                v += __shfl_xor(v, 1);
                v += __shfl_xor(v, 2);
                v += __shfl_xor(v, 4);
                v += __shfl_xor(v, 8);
                if (lr == hh) {
                    if (n < num_dst) er[(size_t)n * 4 + hh] = v;
                    else if (n < num_tot) el[(size_t)(n - num_dst) * 4 + hh] = v;
                }
            }
        }
    } else {
        // ---- coarse bin: scatter packed (src | dloc<<25) into bucket runs
        int bb = (int)blockIdx.x - projB;
        for (int i = threadIdx.x; i < MAXBUK; i += 256) h[i] = 0;
        __syncthreads();
        int base = bb * 8192;
#pragma unroll
        for (int i = 0; i < 32; i++) {
            int idx = base + threadIdx.x + i * 256;
            if (idx < E) atomicAdd(&h[ed[idx] >> BSHIFT], 1);
        }
        __syncthreads();
        for (int i = threadIdx.x; i < nbuk; i += 256)
            cur[i] = h[i] ? atomicAdd(&bukcur[i], h[i]) : 0;
        __syncthreads();
#pragma unroll
        for (int i = 0; i < 32; i++) {
            int idx = base + threadIdx.x + i * 256;
            if (idx < E) {
                int d = ed[idx];
                int pos = atomicAdd(&cur[d >> BSHIFT], 1);
                pairs[pos] = (unsigned)es[idx] | ((unsigned)(d & BMASK) << 25);
            }
        }
    }
}

// ---- fine fill: one block per bucket; LDS-staged in-place permute to CSR;
//      also emits offs[] and counts[]. ----
__global__ __launch_bounds__(256) void k_fillb(unsigned* __restrict__ pairs,
                                               const int* __restrict__ bukstart,
                                               const int* __restrict__ bukcnt,
                                               int* __restrict__ offs,
                                               int* __restrict__ counts, int nd) {
    __shared__ unsigned lp[BCAP];
    __shared__ int h[128], ex[128], cur[128];
    int b = blockIdx.x;
    int s = bukstart[b];
    int cnt = bukcnt[b];
    if (cnt > BCAP) cnt = BCAP;  // statistically impossible; guard anyway
    if (threadIdx.x < 128) h[threadIdx.x] = 0;
    __syncthreads();
    for (int i = threadIdx.x; i < cnt; i += 256) {
        unsigned v = pairs[s + i];
        lp[i] = v;
        atomicAdd(&h[v >> 25], 1);
    }
    __syncthreads();
    if (threadIdx.x < 128) ex[threadIdx.x] = h[threadIdx.x];
    __syncthreads();
    for (int off = 1; off < 128; off <<= 1) {
        int v = (threadIdx.x >= off && threadIdx.x < 128) ? ex[threadIdx.x - off] : 0;
        __syncthreads();
        if (threadIdx.x < 128) ex[threadIdx.x] += v;
        __syncthreads();
    }
    if (threadIdx.x < 128) {
        int e = ex[threadIdx.x] - h[threadIdx.x];
        cur[threadIdx.x] = e;
        int d = (b << BSHIFT) + threadIdx.x;
        if (d < nd) { offs[d] = s + e; counts[d] = h[threadIdx.x]; }
    }
    __syncthreads();
    for (int i = threadIdx.x; i < cnt; i += 256) {
        unsigned v = lp[i];
        int r = atomicAdd(&cur[v >> 25], 1);
        pairs[s + r] = v & 0x1FFFFFFu;  // now csr_src
    }
}

// ---- aggregate: one wave per dst; streaming softmax (no running max — shift
// invariant; inputs bounded, clamp 60 inactive). Coef lanes (h=lane>>4,
// j=lane&15); accumulate 2 edges in parallel across wave halves, each lane
// owning a bf16 column PAIR (dword gather). ----
__global__ __launch_bounds__(256) void k_agg(
        const int* __restrict__ csr_src, const int* __restrict__ offs,
        const int* __restrict__ counts, const float* __restrict__ el,
        const float* __restrict__ er, const unsigned short* __restrict__ projb,
        const float* __restrict__ bias, float* __restrict__ out, int nd) {
    int wave = (blockIdx.x * 256 + threadIdx.x) >> 6;
    int lane = threadIdx.x & 63;
    if (wave >= nd) return;
    int d = wave;
    int j = lane & 15, h = lane >> 4;
    int cp = lane & 31, half = lane >> 5;
    int hp16 = (cp >> 3) << 4;          // base lane of head group owning cols 2cp,2cp+1
    int start = offs[d], deg = counts[d];
    float er_h = er[d * 4 + h];

    float den = 0.f, acc0 = 0.f, acc1 = 0.f;
    for (int base = 0; base < deg; base += 16) {
        int cend = deg - base;
        if (cend > 16) cend = 16;
        int sidx = 0;
        float w = 0.f;
        if (j < cend) {
            sidx = csr_src[start + base + j];
            float t = el[sidx * 4 + h] + er_h;
            t = t > 0.f ? t : NEG_SLOPE * t;
            w = __expf(fminf(t, 60.f));
        }
        den += w;
        if (cend == 16) {
#pragma unroll
            for (int t8 = 0; t8 < 8; t8++) {
                int e = 2 * t8 + half;
                int s2 = __shfl(sidx, e);
                float w2 = __shfl(w, hp16 + e);
                unsigned pv = *(const unsigned*)(projb + (size_t)s2 * 64 + cp * 2);
                acc0 += w2 * __uint_as_float(pv << 16);
                acc1 += w2 * __uint_as_float(pv & 0xffff0000u);
            }
        } else {
            int steps = (cend + 1) >> 1;
            for (int t8 = 0; t8 < steps; t8++) {
                int e = 2 * t8 + half;          // may equal cend: w2=0, s2=0 (safe)
                int s2 = __shfl(sidx, e);
                float w2 = __shfl(w, hp16 + e);
                unsigned pv = *(const unsigned*)(projb + (size_t)s2 * 64 + cp * 2);
                acc0 += w2 * __uint_as_float(pv << 16);
                acc1 += w2 * __uint_as_float(pv & 0xffff0000u);
            }
        }
    }

    // per-head denominator (sum over the 16 j-lanes of each head group)
    den += __shfl_xor(den, 1);
    den += __shfl_xor(den, 2);
    den += __shfl_xor(den, 4);
    den += __shfl_xor(den, 8);
    float den_h = __shfl(den, hp16);

    // combine the two edge-halves
    acc0 += __shfl_xor(acc0, 32);
    acc1 += __shfl_xor(acc1, 32);

    if (half == 0) {
        float rden = den_h > 0.f ? 1.f / den_h : 0.f;
        float2 o;
        o.x = acc0 * rden + bias[cp * 2];
        o.y = acc1 * rden + bias[cp * 2 + 1];
        *(float2*)&out[(size_t)d * 64 + cp * 2] = o;
    }
}

extern "C" void kernel_launch(void* const* d_in, const int* in_sizes, int n_in,
                              void* d_out, int out_size, void* d_ws, size_t ws_size,
                              hipStream_t stream) {
    const float* feat   = (const float*)d_in[0];
    const float* W      = (const float*)d_in[1];
    const float* attn_l = (const float*)d_in[2];
    const float* attn_r = (const float*)d_in[3];
    const float* bias   = (const float*)d_in[4];
    const int*   es     = (const int*)d_in[5];
    const int*   ed     = (const int*)d_in[6];

    const int HD      = in_sizes[2];            // 64
    const int in_f    = in_sizes[1] / HD;       // 128
    const int num_dst = out_size / HD;          // 50000
    const int num_tot = in_sizes[0] / in_f;     // 150000
    const int num_src = num_tot - num_dst;      // 100000
    const int E       = in_sizes[5];            // 1200000

    float* out = (float*)d_out;

    // ws layout (all sections multiples of 4 dwords -> 16B aligned)
    unsigned short* projb = (unsigned short*)d_ws;               // num_src*64 bf16
    float*    el       = (float*)(projb + (size_t)num_src * 64); // num_src*4
    float*    er       = el + (size_t)num_src * 4;               // num_dst*4
    int*      counts   = (int*)(er + (size_t)num_dst * 4);       // num_dst
    int*      offs     = counts + num_dst;                       // num_dst
    int*      bukcnt   = offs + num_dst;                         // MAXBUK
    int*      bukstart = bukcnt + MAXBUK;                        // MAXBUK
    int*      bukcur   = bukstart + MAXBUK;                      // MAXBUK
    unsigned* pairs    = (unsigned*)(bukcur + MAXBUK);           // E (becomes csr_src)
    short*    Wb       = (short*)(pairs + E);                    // HD*in_f bf16

    const int NBUK  = (num_dst + BMASK) >> BSHIFT;               // 391 (<= MAXBUK)
    const int projB = (num_tot + 63) / 64;                       // 2344
    const int binB  = (E + 8191) / 8192;                         // 147

    hipMemsetAsync(bukcnt, 0, MAXBUK * sizeof(int), stream);

    k_bhist<<<(E + 4095) / 4096, 256, 0, stream>>>(ed, bukcnt, W, Wb, HD * in_f, E, NBUK);
    k_bscan<<<1, MAXBUK, 0, stream>>>(bukcnt, bukstart, bukcur, NBUK);

    k_proj_bin<<<projB + binB, 256, 0, stream>>>(
        feat, Wb, attn_l, attn_r, projb, el, er, num_tot, num_dst, projB,
        es, ed, bukcur, pairs, E, NBUK);

    k_fillb<<<NBUK, 256, 0, stream>>>(pairs, bukstart, bukcnt, offs, counts, num_dst);

    k_agg<<<(num_dst * 64 + 255) / 256, 256, 0, stream>>>(
        (const int*)pairs, offs, counts, el, er, projb, bias, out, num_dst);
}

// Round 8
// 124.324 us; speedup vs baseline: 10.1826x; 1.0868x over previous
//
#include <hip/hip_runtime.h>
#include <hip/hip_bf16.h>

// GAT conv: H=4 heads, D=16 (H*D = 64) — hardcoded per reference constants.
// feat: (N_tot, 128) f32, W: (64,128), attn_l/r: (4,16), bias: (64,)
// out: (NUM_DST, 4, 16) f32
//
// Pipeline (6 dispatches): memset | bhist(+W->bf16) | bscan | proj+bin (one
// grid) | fillb | agg. Projection: A and W tiles both staged in swizzled LDS
// (coalesced loads, conflict-free ds_read_b128), MFMA, then f32 accumulators
// transposed through padded LDS so el/er = thread-local dot and projb stores
// are coalesced dwordx4. CSR via two-level XCD-local binning; aggregate is a
// per-dst-wave streaming softmax with dword bf16-pair gathers.

#define NEG_SLOPE 0.2f
#define BSHIFT 7                 // bucket = dst >> 7 (128 dsts per bucket)
#define BMASK  127
#define MAXBUK 512               // supports num_dst <= 65536
#define BCAP   6144              // max edges per bucket (mean ~3070)

typedef __attribute__((ext_vector_type(8))) short bf16x8;  // 8 bf16 (4 VGPRs)
typedef __attribute__((ext_vector_type(4))) float f32x4;

__device__ __forceinline__ short f2bf(float f) {  // RNE f32->bf16 bits
    unsigned u = __float_as_uint(f);
    unsigned r = (u + 0x7fffu + ((u >> 16) & 1u)) >> 16;
    return (short)r;
}
__device__ __forceinline__ unsigned pk2(float a, float b) {  // 2xbf16 dword
    return (unsigned)(unsigned short)f2bf(a) | ((unsigned)(unsigned short)f2bf(b) << 16);
}

// ---- bucket histogram (LDS pre-aggregation) + W fp32->bf16 (first 8 blocks) ----
__global__ __launch_bounds__(256) void k_bhist(const int* __restrict__ ed,
                                               int* __restrict__ bukcnt,
                                               const float* __restrict__ W,
                                               short* __restrict__ Wb, int nW,
                                               int E, int nbuk) {
    if (blockIdx.x < 8) {
#pragma unroll
        for (int i = 0; i < 4; i++) {
            int idx = blockIdx.x * 1024 + i * 256 + threadIdx.x;
            if (idx < nW) Wb[idx] = f2bf(W[idx]);
        }
    }
    __shared__ int h[MAXBUK];
    for (int i = threadIdx.x; i < MAXBUK; i += 256) h[i] = 0;
    __syncthreads();
    int base = blockIdx.x * 4096;
#pragma unroll
    for (int i = 0; i < 16; i++) {
        int idx = base + threadIdx.x + i * 256;
        if (idx < E) atomicAdd(&h[ed[idx] >> BSHIFT], 1);
    }
    __syncthreads();
    for (int i = threadIdx.x; i < nbuk; i += 256)
        if (h[i]) atomicAdd(&bukcnt[i], h[i]);
}

// ---- exclusive scan of bucket counts (nbuk <= 512), init cursors ----
__global__ __launch_bounds__(512) void k_bscan(const int* __restrict__ bukcnt,
                                               int* __restrict__ bukstart,
                                               int* __restrict__ bukcur, int nbuk) {
    __shared__ int sh[MAXBUK];
    int tid = threadIdx.x;
    int c = (tid < nbuk) ? bukcnt[tid] : 0;
    sh[tid] = c;
    __syncthreads();
    for (int off = 1; off < MAXBUK; off <<= 1) {
        int v = (tid >= off) ? sh[tid - off] : 0;
        __syncthreads();
        sh[tid] += v;
        __syncthreads();
    }
    int ex = sh[tid] - c;
    if (tid < nbuk) { bukstart[tid] = ex; bukcur[tid] = ex; }
}

// ---- merged dispatch: MFMA projection (+fused el/er) | coarse bin ----
// blocks [0, projB): proj.  blocks [projB, projB+binB): bin.
__global__ __launch_bounds__(256) void k_proj_bin(
        const float* __restrict__ feat, const short* __restrict__ Wb,
        const float* __restrict__ attn_l, const float* __restrict__ attn_r,
        unsigned short* __restrict__ projb, float* __restrict__ el, float* __restrict__ er,
        int num_tot, int num_dst, int projB,
        const int* __restrict__ es, const int* __restrict__ ed,
        int* __restrict__ bukcur, unsigned* __restrict__ pairs, int E, int nbuk) {
    // union'd LDS: proj path: [0,17408) = A-tile bf16 (16KB) then out f32 [64][68];
    //              [17408, 33792) = W-tile bf16. bin path: h/cur (4KB).
    __shared__ __align__(16) char smem_[17408 + 16384];
    if ((int)blockIdx.x < projB) {
        unsigned short* fs = (unsigned short*)smem_;            // A bf16 [64][128] swz
        float* fsf = (float*)smem_;                             // out f32 [64][68]
        unsigned short* ws = (unsigned short*)(smem_ + 17408);  // W bf16 [64][128] swz
        const int tid = threadIdx.x;
        const int nblk = blockIdx.x * 64;

        // ---- stage A tile: coalesced f32 loads -> bf16 -> swizzled LDS
#pragma unroll
        for (int it = 0; it < 4; it++) {
            int flat = it * 2048 + tid * 8;
            int row = flat >> 7;          // 0..63
            int col = flat & 127;         // multiple of 8
            int grow = nblk + row;
            if (grow >= num_tot) grow = num_tot - 1;  // clamp (outputs guarded)
            const float4* src = (const float4*)(feat + (size_t)grow * 128 + col);
            float4 x = src[0], y = src[1];
            bf16x8 t;
            t[0] = f2bf(x.x); t[1] = f2bf(x.y); t[2] = f2bf(x.z); t[3] = f2bf(x.w);
            t[4] = f2bf(y.x); t[5] = f2bf(y.y); t[6] = f2bf(y.z); t[7] = f2bf(y.w);
            int slot = col >> 3;
            *(bf16x8*)&fs[row * 128 + ((slot ^ (row & 15)) << 3)] = t;
        }
        // ---- stage W tile (already bf16): coalesced 16B loads -> swizzled LDS
#pragma unroll
        for (int it = 0; it < 4; it++) {
            int flat = it * 2048 + tid * 8;
            int row = flat >> 7;
            int col = flat & 127;
            bf16x8 t = *(const bf16x8*)(Wb + row * 128 + col);
            int slot = col >> 3;
            *(bf16x8*)&ws[row * 128 + ((slot ^ (row & 15)) << 3)] = t;
        }
        __syncthreads();

        const int lane = tid & 63;
        const int wv = tid >> 6;
        const int lr = lane & 15;
        const int lg = lane >> 4;

        // A-fragments into registers (fs is reused for output right after)
        bf16x8 afrag[4];
#pragma unroll
        for (int c = 0; c < 4; c++)
            afrag[c] = *(const bf16x8*)&fs[(wv * 16 + lr) * 128 + (((c * 4 + lg) ^ lr) << 3)];
        __syncthreads();  // all A reads done before fsf overwrite

        f32x4 acc[4];
#pragma unroll
        for (int hh = 0; hh < 4; hh++) acc[hh] = f32x4{0.f, 0.f, 0.f, 0.f};
#pragma unroll
        for (int hh = 0; hh < 4; hh++) {
#pragma unroll
            for (int c = 0; c < 4; c++) {
                bf16x8 b = *(const bf16x8*)&ws[(hh * 16 + lr) * 128 + (((c * 4 + lg) ^ lr) << 3)];
                acc[hh] = __builtin_amdgcn_mfma_f32_16x16x32_bf16(afrag[c], b, acc[hh], 0, 0, 0);
            }
        }

        // transpose accumulators through LDS (f32, padded stride 68: conflict-free)
#pragma unroll
        for (int hh = 0; hh < 4; hh++)
#pragma unroll
            for (int r = 0; r < 4; r++)
                fsf[(wv * 16 + lg * 4 + r) * 68 + hh * 16 + lr] = acc[hh][r];
        __syncthreads();

        // output phase: thread = (row, 16-col segment) = (node, head)
        int row = tid >> 2, seg = tid & 3;
        int n = nblk + row;
        if (n < num_tot) {
            const float4* rp = (const float4*)&fsf[row * 68 + seg * 16];
            float4 v0 = rp[0], v1 = rp[1], v2 = rp[2], v3 = rp[3];
            bool is_dst = n < num_dst;
            const float* attn = is_dst ? attn_r : attn_l;
            const float4* ap = (const float4*)&attn[seg * 16];
            float4 a0 = ap[0], a1 = ap[1], a2 = ap[2], a3 = ap[3];
            float e = v0.x * a0.x + v0.y * a0.y + v0.z * a0.z + v0.w * a0.w
                    + v1.x * a1.x + v1.y * a1.y + v1.z * a1.z + v1.w * a1.w
                    + v2.x * a2.x + v2.y * a2.y + v2.z * a2.z + v2.w * a2.w
                    + v3.x * a3.x + v3.y * a3.y + v3.z * a3.z + v3.w * a3.w;
            if (is_dst) {
                er[(size_t)n * 4 + seg] = e;
            } else {
                int sN = n - num_dst;
                el[(size_t)sN * 4 + seg] = e;
                uint4 q0, q1;
                q0.x = pk2(v0.x, v0.y); q0.y = pk2(v0.z, v0.w);
                q0.z = pk2(v1.x, v1.y); q0.w = pk2(v1.z, v1.w);
                q1.x = pk2(v2.x, v2.y); q1.y = pk2(v2.z, v2.w);
                q1.z = pk2(v3.x, v3.y); q1.w = pk2(v3.z, v3.w);
                uint4* dst = (uint4*)(projb + (size_t)sN * 64 + seg * 16);
                dst[0] = q0; dst[1] = q1;
            }
        }
    } else {
        // ---- coarse bin: scatter packed (src | dloc<<25) into bucket runs
        int* h = (int*)smem_;
        int* cur = (int*)(smem_ + 2048);
        int bb = (int)blockIdx.x - projB;
        for (int i = threadIdx.x; i < MAXBUK; i += 256) h[i] = 0;
        __syncthreads();
        int base = bb * 8192;
#pragma unroll
        for (int i = 0; i < 32; i++) {
            int idx = base + threadIdx.x + i * 256;
            if (idx < E) atomicAdd(&h[ed[idx] >> BSHIFT], 1);
        }
        __syncthreads();
        for (int i = threadIdx.x; i < nbuk; i += 256)
            cur[i] = h[i] ? atomicAdd(&bukcur[i], h[i]) : 0;
        __syncthreads();
#pragma unroll
        for (int i = 0; i < 32; i++) {
            int idx = base + threadIdx.x + i * 256;
            if (idx < E) {
                int d = ed[idx];
                int pos = atomicAdd(&cur[d >> BSHIFT], 1);
                pairs[pos] = (unsigned)es[idx] | ((unsigned)(d & BMASK) << 25);
            }
        }
    }
}

// ---- fine fill: one block per bucket; LDS-staged in-place permute to CSR;
//      also emits offs[] and counts[]. ----
__global__ __launch_bounds__(256) void k_fillb(unsigned* __restrict__ pairs,
                                               const int* __restrict__ bukstart,
                                               const int* __restrict__ bukcnt,
                                               int* __restrict__ offs,
                                               int* __restrict__ counts, int nd) {
    __shared__ unsigned lp[BCAP];
    __shared__ int h[128], ex[128], cur[128];
    int b = blockIdx.x;
    int s = bukstart[b];
    int cnt = bukcnt[b];
    if (cnt > BCAP) cnt = BCAP;  // statistically impossible; guard anyway
    if (threadIdx.x < 128) h[threadIdx.x] = 0;
    __syncthreads();
    for (int i = threadIdx.x; i < cnt; i += 256) {
        unsigned v = pairs[s + i];
        lp[i] = v;
        atomicAdd(&h[v >> 25], 1);
    }
    __syncthreads();
    if (threadIdx.x < 128) ex[threadIdx.x] = h[threadIdx.x];
    __syncthreads();
    for (int off = 1; off < 128; off <<= 1) {
        int v = (threadIdx.x >= off && threadIdx.x < 128) ? ex[threadIdx.x - off] : 0;
        __syncthreads();
        if (threadIdx.x < 128) ex[threadIdx.x] += v;
        __syncthreads();
    }
    if (threadIdx.x < 128) {
        int e = ex[threadIdx.x] - h[threadIdx.x];
        cur[threadIdx.x] = e;
        int d = (b << BSHIFT) + threadIdx.x;
        if (d < nd) { offs[d] = s + e; counts[d] = h[threadIdx.x]; }
    }
    __syncthreads();
    for (int i = threadIdx.x; i < cnt; i += 256) {
        unsigned v = lp[i];
        int r = atomicAdd(&cur[v >> 25], 1);
        pairs[s + r] = v & 0x1FFFFFFu;  // now csr_src
    }
}

// ---- aggregate: one wave per dst; streaming softmax (no running max — shift
// invariant; inputs bounded, clamp 60 inactive). Coef lanes (h=lane>>4,
// j=lane&15); accumulate 2 edges in parallel across wave halves, each lane
// owning a bf16 column PAIR (dword gather). ----
__global__ __launch_bounds__(256) void k_agg(
        const int* __restrict__ csr_src, const int* __restrict__ offs,
        const int* __restrict__ counts, const float* __restrict__ el,
        const float* __restrict__ er, const unsigned short* __restrict__ projb,
        const float* __restrict__ bias, float* __restrict__ out, int nd) {
    int wave = (blockIdx.x * 256 + threadIdx.x) >> 6;
    int lane = threadIdx.x & 63;
    if (wave >= nd) return;
    int d = wave;
    int j = lane & 15, h = lane >> 4;
    int cp = lane & 31, half = lane >> 5;
    int hp16 = (cp >> 3) << 4;          // base lane of head group owning cols 2cp,2cp+1
    int start = offs[d], deg = counts[d];
    float er_h = er[d * 4 + h];

    float den = 0.f, acc0 = 0.f, acc1 = 0.f;
    for (int base = 0; base < deg; base += 16) {
        int cend = deg - base;
        if (cend > 16) cend = 16;
        int sidx = 0;
        float w = 0.f;
        if (j < cend) {
            sidx = csr_src[start + base + j];
            float t = el[sidx * 4 + h] + er_h;
            t = t > 0.f ? t : NEG_SLOPE * t;
            w = __expf(fminf(t, 60.f));
        }
        den += w;
        if (cend == 16) {
#pragma unroll
            for (int t8 = 0; t8 < 8; t8++) {
                int e = 2 * t8 + half;
                int s2 = __shfl(sidx, e);
                float w2 = __shfl(w, hp16 + e);
                unsigned pv = *(const unsigned*)(projb + (size_t)s2 * 64 + cp * 2);
                acc0 += w2 * __uint_as_float(pv << 16);
                acc1 += w2 * __uint_as_float(pv & 0xffff0000u);
            }
        } else {
            int steps = (cend + 1) >> 1;
            for (int t8 = 0; t8 < steps; t8++) {
                int e = 2 * t8 + half;          // may equal cend: w2=0, s2=0 (safe)
                int s2 = __shfl(sidx, e);
                float w2 = __shfl(w, hp16 + e);
                unsigned pv = *(const unsigned*)(projb + (size_t)s2 * 64 + cp * 2);
                acc0 += w2 * __uint_as_float(pv << 16);
                acc1 += w2 * __uint_as_float(pv & 0xffff0000u);
            }
        }
    }

    // per-head denominator (sum over the 16 j-lanes of each head group)
    den += __shfl_xor(den, 1);
    den += __shfl_xor(den, 2);
    den += __shfl_xor(den, 4);
    den += __shfl_xor(den, 8);
    float den_h = __shfl(den, hp16);

    // combine the two edge-halves
    acc0 += __shfl_xor(acc0, 32);
    acc1 += __shfl_xor(acc1, 32);

    if (half == 0) {
        float rden = den_h > 0.f ? 1.f / den_h : 0.f;
        float2 o;
        o.x = acc0 * rden + bias[cp * 2];
        o.y = acc1 * rden + bias[cp * 2 + 1];
        *(float2*)&out[(size_t)d * 64 + cp * 2] = o;
    }
}

extern "C" void kernel_launch(void* const* d_in, const int* in_sizes, int n_in,
                              void* d_out, int out_size, void* d_ws, size_t ws_size,
                              hipStream_t stream) {
    const float* feat   = (const float*)d_in[0];
    const float* W      = (const float*)d_in[1];
    const float* attn_l = (const float*)d_in[2];
    const float* attn_r = (const float*)d_in[3];
    const float* bias   = (const float*)d_in[4];
    const int*   es     = (const int*)d_in[5];
    const int*   ed     = (const int*)d_in[6];

    const int HD      = in_sizes[2];            // 64
    const int in_f    = in_sizes[1] / HD;       // 128
    const int num_dst = out_size / HD;          // 50000
    const int num_tot = in_sizes[0] / in_f;     // 150000
    const int num_src = num_tot - num_dst;      // 100000
    const int E       = in_sizes[5];            // 1200000

    float* out = (float*)d_out;

    // ws layout (all sections multiples of 4 dwords -> 16B aligned)
    unsigned short* projb = (unsigned short*)d_ws;               // num_src*64 bf16
    float*    el       = (float*)(projb + (size_t)num_src * 64); // num_src*4
    float*    er       = el + (size_t)num_src * 4;               // num_dst*4
    int*      counts   = (int*)(er + (size_t)num_dst * 4);       // num_dst
    int*      offs     = counts + num_dst;                       // num_dst
    int*      bukcnt   = offs + num_dst;                         // MAXBUK
    int*      bukstart = bukcnt + MAXBUK;                        // MAXBUK
    int*      bukcur   = bukstart + MAXBUK;                      // MAXBUK
    unsigned* pairs    = (unsigned*)(bukcur + MAXBUK);           // E (becomes csr_src)
    short*    Wb       = (short*)(pairs + E);                    // HD*in_f bf16

    const int NBUK  = (num_dst + BMASK) >> BSHIFT;               // 391 (<= MAXBUK)
    const int projB = (num_tot + 63) / 64;                       // 2344
    const int binB  = (E + 8191) / 8192;                         // 147

    hipMemsetAsync(bukcnt, 0, MAXBUK * sizeof(int), stream);

    k_bhist<<<(E + 4095) / 4096, 256, 0, stream>>>(ed, bukcnt, W, Wb, HD * in_f, E, NBUK);
    k_bscan<<<1, MAXBUK, 0, stream>>>(bukcnt, bukstart, bukcur, NBUK);

    k_proj_bin<<<projB + binB, 256, 0, stream>>>(
        feat, Wb, attn_l, attn_r, projb, el, er, num_tot, num_dst, projB,
        es, ed, bukcur, pairs, E, NBUK);

    k_fillb<<<NBUK, 256, 0, stream>>>(pairs, bukstart, bukcnt, offs, counts, num_dst);

    k_agg<<<(num_dst * 64 + 255) / 256, 256, 0, stream>>>(
        (const int*)pairs, offs, counts, el, er, projb, bias, out, num_dst);
}